// Round 1
// baseline (379.391 us; speedup 1.0000x reference)
//
#include <hip/hip_runtime.h>
#include <hip/hip_bf16.h>
#include <cstdint>
#include <cstddef>

typedef _Float16 f16;
typedef _Float16 f16x8 __attribute__((ext_vector_type(8)));
typedef _Float16 f16x4 __attribute__((ext_vector_type(4)));
typedef float    f32x4 __attribute__((ext_vector_type(4)));

#define DM 1024   // d_model
#define NBE 256   // entities per batch row

// ---------------- fp32 -> fp16 convert (vectorized) ----------------
__global__ __launch_bounds__(256) void conv_f32_f16(const float* __restrict__ in,
                                                    f16* __restrict__ out, int n) {
  int i = (blockIdx.x * 256 + threadIdx.x) * 4;
  if (i >= n) return;
  float4 v = *(const float4*)(in + i);
  f16x4 o; o.x = (f16)v.x; o.y = (f16)v.y; o.z = (f16)v.z; o.w = (f16)v.w;
  *(f16x4*)(out + i) = o;
}

// ---------------- gather entity rows -> fp16 (zeros for idx<0) ----------------
__global__ __launch_bounds__(256) void gather_f16(const float* __restrict__ emb,
                                                  const int* __restrict__ idx,
                                                  f16* __restrict__ out) {
  int slot = blockIdx.x;           // 0..4095
  int e = idx[slot];
  int c = threadIdx.x * 4;
  f16x4 o;
  if (e < 0) {
    o.x = (f16)0.f; o.y = (f16)0.f; o.z = (f16)0.f; o.w = (f16)0.f;
  } else {
    float4 v = *(const float4*)(emb + (size_t)e * DM + c);
    o.x = (f16)v.x; o.y = (f16)v.y; o.z = (f16)v.z; o.w = (f16)v.w;
  }
  *(f16x4*)(out + (size_t)slot * DM + c) = o;
}

// ---------------- 1024x1024 fp32 transpose -> fp16 ----------------
__global__ __launch_bounds__(256) void tr_f32_f16(const float* __restrict__ in,
                                                  f16* __restrict__ out) {
  __shared__ float t[64][65];
  int bi = blockIdx.y * 64, bj = blockIdx.x * 64;
  int tx = threadIdx.x & 63, ty = threadIdx.x >> 6;
#pragma unroll
  for (int k = 0; k < 16; ++k) {
    int r = ty * 16 + k;
    t[r][tx] = in[(size_t)(bi + r) * DM + bj + tx];
  }
  __syncthreads();
#pragma unroll
  for (int k = 0; k < 16; ++k) {
    int r = ty * 16 + k;
    out[(size_t)(bj + r) * DM + bi + tx] = (f16)t[tx][r];
  }
}

// ---------------- batched f16 transpose: E (b,256,1024) -> Et (b,1024,256) ----------------
__global__ __launch_bounds__(256) void tr_et(const f16* __restrict__ E,
                                             f16* __restrict__ Et) {
  __shared__ f16 t[64][65];
  int b = blockIdx.z;
  int bi = blockIdx.y * 64;  // slot dim (256)
  int bj = blockIdx.x * 64;  // d dim (1024)
  int tx = threadIdx.x & 63, ty = threadIdx.x >> 6;
  const f16* Eb = E + (size_t)b * NBE * DM;
  f16* Eo = Et + (size_t)b * DM * NBE;
#pragma unroll
  for (int k = 0; k < 16; ++k) {
    int r = ty * 16 + k;
    t[r][tx] = Eb[(size_t)(bi + r) * DM + bj + tx];
  }
  __syncthreads();
#pragma unroll
  for (int k = 0; k < 16; ++k) {
    int r = ty * 16 + k;
    Eo[(size_t)(bj + r) * NBE + bi + tx] = t[tx][r];
  }
}

// ---------------- c[slot] = bq . E[slot,:] ----------------
__global__ __launch_bounds__(256) void c_kernel(const f16* __restrict__ E,
                                                const float* __restrict__ bq,
                                                float* __restrict__ cvec) {
  int w = threadIdx.x >> 6, lane = threadIdx.x & 63;
  int row = blockIdx.x * 4 + w;    // 0..4095
  const f16* e = E + (size_t)row * DM;
  float s = 0.f;
#pragma unroll
  for (int k = 0; k < 16; ++k) {
    int i = lane + k * 64;
    s += (float)e[i] * bq[i];
  }
#pragma unroll
  for (int d = 1; d < 64; d <<= 1) s += __shfl_xor(s, d);
  if (lane == 0) cvec[row] = s;
}

// ---------------- generic TN GEMM: C[M,N] = A[M,K] @ B[N,K]^T (+epilogue) --------------
// EPI 0: f16 out, no bias (G, T')
// EPI 1: f16 out, +bias, zero row if rowidx[r]<0 (E)
// EPI 2: f32 out, +bias (O)
// 128x128 tile, BK=64, 4 waves (2x2), 16x16x32 f16 MFMA, XOR-swizzled LDS,
// T14-style split staging (issue loads early, ds_write after compute).
template <int EPI>
__global__ __launch_bounds__(256) void gemm_tn(
    const f16* __restrict__ A, const f16* __restrict__ B,
    const float* __restrict__ bias, const int* __restrict__ rowidx,
    void* __restrict__ C, int M, int N, int K) {
  __shared__ __align__(16) f16 smA[2][128 * 64];
  __shared__ __align__(16) f16 smB[2][128 * 64];
  int tid = threadIdx.x;
  int m0 = blockIdx.y * 128, n0 = blockIdx.x * 128;
  int lane = tid & 63, w = tid >> 6;
  int wr = w >> 1, wc = w & 1;
  int l15 = lane & 15, lhi = lane >> 4;
  const f16* Ab = A + (size_t)m0 * K;
  const f16* Bb = B + (size_t)n0 * K;

  f32x4 acc[4][4];
  f32x4 z4 = {0.f, 0.f, 0.f, 0.f};
#pragma unroll
  for (int i = 0; i < 4; ++i)
#pragma unroll
    for (int j = 0; j < 4; ++j) acc[i][j] = z4;

  f16x8 ra[4], rb[4];
  // stage tile 0
#pragma unroll
  for (int p = 0; p < 4; ++p) {
    int e = p * 2048 + tid * 8;
    int row = e >> 6, c8 = (e & 63) >> 3;
    ra[p] = *(const f16x8*)(Ab + (size_t)row * K + c8 * 8);
    rb[p] = *(const f16x8*)(Bb + (size_t)row * K + c8 * 8);
  }
#pragma unroll
  for (int p = 0; p < 4; ++p) {
    int e = p * 2048 + tid * 8;
    int row = e >> 6, c8 = (e & 63) >> 3;
    int off = row * 64 + ((c8 ^ (row & 7)) << 3);
    *(f16x8*)(&smA[0][off]) = ra[p];
    *(f16x8*)(&smB[0][off]) = rb[p];
  }

  int nk = K >> 6;
  for (int kt = 0; kt < nk; ++kt) {
    int cur = kt & 1;
    bool pre = (kt + 1 < nk);
    __syncthreads();
    if (pre) {
      const f16* An = Ab + (kt + 1) * 64;
      const f16* Bn = Bb + (kt + 1) * 64;
#pragma unroll
      for (int p = 0; p < 4; ++p) {
        int e = p * 2048 + tid * 8;
        int row = e >> 6, c8 = (e & 63) >> 3;
        ra[p] = *(const f16x8*)(An + (size_t)row * K + c8 * 8);
        rb[p] = *(const f16x8*)(Bn + (size_t)row * K + c8 * 8);
      }
    }
    const f16* As = smA[cur];
    const f16* Bs = smB[cur];
#pragma unroll
    for (int kk = 0; kk < 2; ++kk) {
      int c8 = kk * 4 + lhi;
      f16x8 af[4], bf[4];
#pragma unroll
      for (int mi = 0; mi < 4; ++mi) {
        int r = wr * 64 + mi * 16 + l15;
        af[mi] = *(const f16x8*)(As + r * 64 + ((c8 ^ (r & 7)) << 3));
      }
#pragma unroll
      for (int ni = 0; ni < 4; ++ni) {
        int r = wc * 64 + ni * 16 + l15;
        bf[ni] = *(const f16x8*)(Bs + r * 64 + ((c8 ^ (r & 7)) << 3));
      }
#pragma unroll
      for (int mi = 0; mi < 4; ++mi)
#pragma unroll
        for (int ni = 0; ni < 4; ++ni)
          acc[mi][ni] = __builtin_amdgcn_mfma_f32_16x16x32_f16(af[mi], bf[ni], acc[mi][ni], 0, 0, 0);
    }
    if (pre) {
#pragma unroll
      for (int p = 0; p < 4; ++p) {
        int e = p * 2048 + tid * 8;
        int row = e >> 6, c8 = (e & 63) >> 3;
        int off = row * 64 + ((c8 ^ (row & 7)) << 3);
        *(f16x8*)(&smA[cur ^ 1][off]) = ra[p];
        *(f16x8*)(&smB[cur ^ 1][off]) = rb[p];
      }
    }
  }

  // epilogue: C/D layout col=lane&15, row=(lane>>4)*4+reg  [learn_hip m89]
#pragma unroll
  for (int mi = 0; mi < 4; ++mi) {
#pragma unroll
    for (int j = 0; j < 4; ++j) {
      int r = m0 + wr * 64 + mi * 16 + lhi * 4 + j;
      bool zero = false;
      if (EPI == 1) zero = (rowidx[r] < 0);
#pragma unroll
      for (int ni = 0; ni < 4; ++ni) {
        int cN = n0 + wc * 64 + ni * 16 + l15;
        float v = acc[mi][ni][j];
        if (EPI >= 1) v += bias[cN];
        if (EPI == 1 && zero) v = 0.f;
        if (EPI == 2) ((float*)C)[(size_t)r * N + cN] = v;
        else          ((f16*)C)[(size_t)r * N + cN] = (f16)v;
      }
    }
  }
}

// ---------------- fused attention: S=Qh@T'^T + c - mask, softmax, V=(P/32)@Et -------
// grid (16 L-tiles of 64, 16 batches), 4 waves; wave w owns rows w*16..w*16+15.
__global__ __launch_bounds__(256) void attn_kernel(
    const f16* __restrict__ Qh, const f16* __restrict__ Tp,
    const f16* __restrict__ Et, const float* __restrict__ cvec,
    const int* __restrict__ idx, f16* __restrict__ V) {
  __shared__ __align__(16) f16 smQ[64 * 64];     // 8KB
  __shared__ __align__(16) f16 smB[256 * 64];    // 32KB: T' tiles, then Et tiles
  __shared__ __align__(16) f16 smP[64 * 256];    // 32KB, swizzled
  int b = blockIdx.y, lt = blockIdx.x;
  int tid = threadIdx.x, lane = tid & 63, w = tid >> 6;
  int l15 = lane & 15, lhi = lane >> 4;
  const f16* Qbase = Qh + (size_t)(b * 1024 + lt * 64) * DM;
  const f16* Tbase = Tp + (size_t)b * NBE * DM;

  f32x4 z4 = {0.f, 0.f, 0.f, 0.f};
  f32x4 accs[16];
#pragma unroll
  for (int i = 0; i < 16; ++i) accs[i] = z4;

  // ---- phase 1: S tile (64 x 256) over K=1024, BK=64 ----
  for (int kt = 0; kt < 16; ++kt) {
    __syncthreads();
#pragma unroll
    for (int p = 0; p < 2; ++p) {
      int e = p * 2048 + tid * 8;
      int row = e >> 6, c8 = (e & 63) >> 3;
      *(f16x8*)(smQ + row * 64 + ((c8 ^ (row & 7)) << 3)) =
          *(const f16x8*)(Qbase + (size_t)row * DM + kt * 64 + c8 * 8);
    }
#pragma unroll
    for (int p = 0; p < 8; ++p) {
      int e = p * 2048 + tid * 8;
      int row = e >> 6, c8 = (e & 63) >> 3;
      *(f16x8*)(smB + row * 64 + ((c8 ^ (row & 7)) << 3)) =
          *(const f16x8*)(Tbase + (size_t)row * DM + kt * 64 + c8 * 8);
    }
    __syncthreads();
#pragma unroll
    for (int kk = 0; kk < 2; ++kk) {
      int c8 = kk * 4 + lhi;
      int qr = w * 16 + l15;
      f16x8 aq = *(const f16x8*)(smQ + qr * 64 + ((c8 ^ (qr & 7)) << 3));
#pragma unroll
      for (int ni = 0; ni < 16; ++ni) {
        int er = ni * 16 + l15;
        f16x8 bb = *(const f16x8*)(smB + er * 64 + ((c8 ^ (er & 7)) << 3));
        accs[ni] = __builtin_amdgcn_mfma_f32_16x16x32_f16(aq, bb, accs[ni], 0, 0, 0);
      }
    }
  }

  // ---- phase 2: wave-parallel softmax over 256 cols (16 frags x 16 lanes) ----
  float cv[16];
#pragma unroll
  for (int ni = 0; ni < 16; ++ni) {
    int slot = b * NBE + ni * 16 + l15;
    float m = (idx[slot] < 0) ? -100000.0f : 0.0f;
    cv[ni] = cvec[slot] + m;
  }
#pragma unroll
  for (int j = 0; j < 4; ++j) {
    float mx = -3.0e38f;
#pragma unroll
    for (int ni = 0; ni < 16; ++ni) mx = fmaxf(mx, accs[ni][j] + cv[ni]);
    mx = fmaxf(mx, __shfl_xor(mx, 1));
    mx = fmaxf(mx, __shfl_xor(mx, 2));
    mx = fmaxf(mx, __shfl_xor(mx, 4));
    mx = fmaxf(mx, __shfl_xor(mx, 8));
    float sum = 0.f;
    float pv[16];
#pragma unroll
    for (int ni = 0; ni < 16; ++ni) { pv[ni] = __expf(accs[ni][j] + cv[ni] - mx); sum += pv[ni]; }
    sum += __shfl_xor(sum, 1);
    sum += __shfl_xor(sum, 2);
    sum += __shfl_xor(sum, 4);
    sum += __shfl_xor(sum, 8);
    float inv = 1.0f / sum;
    int r = w * 16 + lhi * 4 + j;
#pragma unroll
    for (int ni = 0; ni < 16; ++ni) {
      int col = ni * 16 + l15;
      int cc8 = col >> 3;
      smP[r * 256 + ((cc8 ^ (r & 7)) << 3) + (col & 7)] = (f16)(pv[ni] * inv);
    }
  }

  // ---- phase 3: V = P @ Et_b, 4 chunks of 256 output dims, K=256 in BK=64 subtiles --
  const f16* Etb = Et + (size_t)b * DM * NBE;
  f16* Vbase = V + (size_t)(b * 1024 + lt * 64) * DM;
  for (int dc = 0; dc < 4; ++dc) {
    f32x4 accv[16];
#pragma unroll
    for (int i = 0; i < 16; ++i) accv[i] = z4;
    for (int ks = 0; ks < 4; ++ks) {
      __syncthreads();
#pragma unroll
      for (int p = 0; p < 8; ++p) {
        int e = p * 2048 + tid * 8;
        int row = e >> 6, c8 = (e & 63) >> 3;
        *(f16x8*)(smB + row * 64 + ((c8 ^ (row & 7)) << 3)) =
            *(const f16x8*)(Etb + (size_t)(dc * 256 + row) * NBE + ks * 64 + c8 * 8);
      }
      __syncthreads();
#pragma unroll
      for (int kk = 0; kk < 2; ++kk) {
        int pc8 = ks * 8 + kk * 4 + lhi;
        int qr = w * 16 + l15;
        f16x8 ap = *(const f16x8*)(smP + qr * 256 + ((pc8 ^ (qr & 7)) << 3));
        int c8 = kk * 4 + lhi;
#pragma unroll
        for (int ni = 0; ni < 16; ++ni) {
          int er = ni * 16 + l15;
          f16x8 bv = *(const f16x8*)(smB + er * 64 + ((c8 ^ (er & 7)) << 3));
          accv[ni] = __builtin_amdgcn_mfma_f32_16x16x32_f16(ap, bv, accv[ni], 0, 0, 0);
        }
      }
    }
#pragma unroll
    for (int ni = 0; ni < 16; ++ni) {
#pragma unroll
      for (int j = 0; j < 4; ++j) {
        int r = w * 16 + lhi * 4 + j;
        int col = dc * 256 + ni * 16 + l15;
        Vbase[(size_t)r * DM + col] = (f16)(accv[ni][j] * 0.03125f);
      }
    }
  }
}

// ---------------- in-place LayerNorm over D=1024 ----------------
__global__ __launch_bounds__(256) void ln_kernel(float* __restrict__ X,
                                                 const float* __restrict__ g,
                                                 const float* __restrict__ bta) {
  size_t row = blockIdx.x;
  float* x = X + row * DM;
  int tid = threadIdx.x;
  float4 v = *(const float4*)(x + tid * 4);
  float s = v.x + v.y + v.z + v.w;
  float q = v.x * v.x + v.y * v.y + v.z * v.z + v.w * v.w;
#pragma unroll
  for (int d = 1; d < 64; d <<= 1) { s += __shfl_xor(s, d); q += __shfl_xor(q, d); }
  __shared__ float ss[4], qq[4];
  int w = tid >> 6, lane = tid & 63;
  if (lane == 0) { ss[w] = s; qq[w] = q; }
  __syncthreads();
  s = ss[0] + ss[1] + ss[2] + ss[3];
  q = qq[0] + qq[1] + qq[2] + qq[3];
  float mu = s * (1.0f / DM);
  float var = q * (1.0f / DM) - mu * mu;
  float rs = rsqrtf(var + 1e-5f);
  float4 gg = *(const float4*)(g + tid * 4);
  float4 bb = *(const float4*)(bta + tid * 4);
  float4 o;
  o.x = (v.x - mu) * rs * gg.x + bb.x;
  o.y = (v.y - mu) * rs * gg.y + bb.y;
  o.z = (v.z - mu) * rs * gg.z + bb.z;
  o.w = (v.w - mu) * rs * gg.w + bb.w;
  *(float4*)(x + tid * 4) = o;
}

extern "C" void kernel_launch(void* const* d_in, const int* in_sizes, int n_in,
                              void* d_out, int out_size, void* d_ws, size_t ws_size,
                              hipStream_t stream) {
  const float* query   = (const float*)d_in[0];
  const float* ent_emb = (const float*)d_in[1];
  const int*   idx     = (const int*)d_in[2];
  // d_in[3] = max_entity_number (unused by reference math)
  const float* WQ_w = (const float*)d_in[4];
  const float* WQ_b = (const float*)d_in[5];
  const float* WK_w = (const float*)d_in[6];
  const float* WK_b = (const float*)d_in[7];
  const float* WO_w = (const float*)d_in[8];
  const float* WO_b = (const float*)d_in[9];
  const float* ln_g = (const float*)d_in[10];
  const float* ln_b = (const float*)d_in[11];
  float* out = (float*)d_out;

  char* p = (char*)d_ws;
  f16* queryh = (f16*)p;  p += (size_t)16 * 1024 * 1024 * 2;  // 32MB
  f16* Egh    = (f16*)p;  p += (size_t)4096 * 1024 * 2;       // 8MB
  f16* WQt    = (f16*)p;  p += (size_t)1024 * 1024 * 2;
  f16* WKt    = (f16*)p;  p += (size_t)1024 * 1024 * 2;
  f16* WKr    = (f16*)p;  p += (size_t)1024 * 1024 * 2;
  f16* WOr    = (f16*)p;  p += (size_t)1024 * 1024 * 2;
  f16* G      = (f16*)p;  p += (size_t)1024 * 1024 * 2;
  f16* Tp     = (f16*)p;  p += (size_t)4096 * 1024 * 2;       // T' = Eg @ G^T
  f16* E      = (f16*)p;  p += (size_t)4096 * 1024 * 2;
  f16* Et     = (f16*)p;  p += (size_t)16 * 1024 * 256 * 2;
  f16* V      = (f16*)p;  p += (size_t)16 * 1024 * 1024 * 2;  // 32MB
  float* cvec = (float*)p; p += (size_t)4096 * 4;

  // conversions / transposes / gather
  conv_f32_f16<<<16384, 256, 0, stream>>>(query, queryh, 16 * 1024 * 1024);
  conv_f32_f16<<<1024, 256, 0, stream>>>(WK_w, WKr, 1024 * 1024);
  conv_f32_f16<<<1024, 256, 0, stream>>>(WO_w, WOr, 1024 * 1024);
  tr_f32_f16<<<dim3(16, 16), 256, 0, stream>>>(WQ_w, WQt);
  tr_f32_f16<<<dim3(16, 16), 256, 0, stream>>>(WK_w, WKt);
  gather_f16<<<4096, 256, 0, stream>>>(ent_emb, idx, Egh);

  // G = WQ^T @ WK (softmax row-constant term dropped; Q never materialized)
  gemm_tn<0><<<dim3(8, 8), 256, 0, stream>>>(WQt, WKt, nullptr, nullptr, G, 1024, 1024, 1024);
  // T' = Eg @ G^T   (so S = query @ T'^T)
  gemm_tn<0><<<dim3(8, 32), 256, 0, stream>>>(Egh, G, nullptr, nullptr, Tp, 4096, 1024, 1024);
  // E = (Eg @ WK^T + bk) * mask
  gemm_tn<1><<<dim3(8, 32), 256, 0, stream>>>(Egh, WKr, WK_b, idx, E, 4096, 1024, 1024);
  // c[slot] = bq . E[slot]
  c_kernel<<<1024, 256, 0, stream>>>(E, WQ_b, cvec);
  // Et = per-batch transpose of E
  tr_et<<<dim3(16, 4, 16), 256, 0, stream>>>(E, Et);
  // fused attention -> V (pre-scaled by d^-0.5)
  attn_kernel<<<dim3(16, 16), 256, 0, stream>>>(queryh, Tp, Et, cvec, idx, V);
  // O = V @ WO^T + bo  (fp32 into d_out)
  gemm_tn<2><<<dim3(8, 128), 256, 0, stream>>>(V, WOr, WO_b, nullptr, out, 16384, 1024, 1024);
  // in-place LayerNorm
  ln_kernel<<<16384, 256, 0, stream>>>(out, ln_g, ln_b);
}

// Round 2
// 326.905 us; speedup vs baseline: 1.1606x; 1.1606x over previous
//
#include <hip/hip_runtime.h>
#include <hip/hip_bf16.h>
#include <cstdint>
#include <cstddef>

typedef _Float16 f16;
typedef _Float16 f16x8 __attribute__((ext_vector_type(8)));
typedef _Float16 f16x4 __attribute__((ext_vector_type(4)));
typedef float    f32x4 __attribute__((ext_vector_type(4)));

#define DM 1024   // d_model
#define NBE 256   // entities per batch row

// ---------------- fp32 -> fp16 convert (vectorized) ----------------
__global__ __launch_bounds__(256) void conv_f32_f16(const float* __restrict__ in,
                                                    f16* __restrict__ out, int n) {
  int i = (blockIdx.x * 256 + threadIdx.x) * 4;
  if (i >= n) return;
  float4 v = *(const float4*)(in + i);
  f16x4 o; o.x = (f16)v.x; o.y = (f16)v.y; o.z = (f16)v.z; o.w = (f16)v.w;
  *(f16x4*)(out + i) = o;
}

// ---------------- dual 1024x1024 fp32 transpose -> fp16 (WQt, WKt) ----------------
__global__ __launch_bounds__(256) void tr2(const float* __restrict__ in0,
                                           const float* __restrict__ in1,
                                           f16* __restrict__ out0,
                                           f16* __restrict__ out1) {
  const float* in = blockIdx.z ? in1 : in0;
  f16* out = blockIdx.z ? out1 : out0;
  __shared__ float t[64][65];
  int bi = blockIdx.y * 64, bj = blockIdx.x * 64;
  int tx = threadIdx.x & 63, ty = threadIdx.x >> 6;
#pragma unroll
  for (int k = 0; k < 16; ++k) {
    int r = ty * 16 + k;
    t[r][tx] = in[(size_t)(bi + r) * DM + bj + tx];
  }
  __syncthreads();
#pragma unroll
  for (int k = 0; k < 16; ++k) {
    int r = ty * 16 + k;
    out[(size_t)(bj + r) * DM + bi + tx] = (f16)t[tx][r];
  }
}

// ---------------- gather entity rows -> fp16 (zeros for idx<0) ----------------
__global__ __launch_bounds__(256) void gather_f16(const float* __restrict__ emb,
                                                  const int* __restrict__ idx,
                                                  f16* __restrict__ out) {
  int slot = blockIdx.x;           // 0..4095
  int e = idx[slot];
  int c = threadIdx.x * 4;
  f16x4 o;
  if (e < 0) {
    o.x = (f16)0.f; o.y = (f16)0.f; o.z = (f16)0.f; o.w = (f16)0.f;
  } else {
    float4 v = *(const float4*)(emb + (size_t)e * DM + c);
    o.x = (f16)v.x; o.y = (f16)v.y; o.z = (f16)v.z; o.w = (f16)v.w;
  }
  *(f16x4*)(out + (size_t)slot * DM + c) = o;
}

// ---------------- u[k] = sum_d bq[d]*WK[d,k]; u[1024] = bk.bq ----------------
__global__ __launch_bounds__(256) void coldot(const float* __restrict__ WK,
                                              const float* __restrict__ bq,
                                              const float* __restrict__ bk,
                                              float* __restrict__ u) {
  if (blockIdx.x < 4) {
    int k = blockIdx.x * 256 + threadIdx.x;
    float s = 0.f;
    for (int d = 0; d < 1024; ++d) s += bq[d] * WK[(size_t)d * 1024 + k];
    u[k] = s;
  } else {
    float s = 0.f;
    for (int i = threadIdx.x; i < 1024; i += 256) s += bk[i] * bq[i];
#pragma unroll
    for (int d = 1; d < 64; d <<= 1) s += __shfl_xor(s, d);
    __shared__ float sm[4];
    int w = threadIdx.x >> 6;
    if ((threadIdx.x & 63) == 0) sm[w] = s;
    __syncthreads();
    if (threadIdx.x == 0) u[1024] = sm[0] + sm[1] + sm[2] + sm[3];
  }
}

// ---------------- out[r] = A[r,:] . v (f32, 1024) ----------------
__global__ __launch_bounds__(256) void rowdot(const float* __restrict__ A,
                                              const float* __restrict__ v,
                                              float* __restrict__ out) {
  int w = threadIdx.x >> 6, lane = threadIdx.x & 63;
  int r = blockIdx.x * 4 + w;
  const float* a = A + (size_t)r * 1024;
  float s = 0.f;
#pragma unroll
  for (int i = 0; i < 16; ++i) s += a[lane + i * 64] * v[lane + i * 64];
#pragma unroll
  for (int d = 1; d < 64; d <<= 1) s += __shfl_xor(s, d);
  if (lane == 0) out[r] = s;
}

// ---------------- cvec[n] = Eg[n,:].u + u[1024] ----------------
__global__ __launch_bounds__(256) void cvec_k(const f16* __restrict__ Eg,
                                              const float* __restrict__ u,
                                              float* __restrict__ cvec) {
  int w = threadIdx.x >> 6, lane = threadIdx.x & 63;
  int n = blockIdx.x * 4 + w;
  const f16* e = Eg + (size_t)n * 1024;
  float s = 0.f;
#pragma unroll
  for (int i = 0; i < 16; ++i) { int k = lane + i * 64; s += (float)e[k] * u[k]; }
#pragma unroll
  for (int d = 1; d < 64; d <<= 1) s += __shfl_xor(s, d);
  if (lane == 0) cvec[n] = s + u[1024];
}

// ---------------- generic TN GEMM core: C[M,N] = A[M,K] @ B[N,K]^T ----------------
// EPI 0: f16 out, plain
// EPI 3: f16 out, + rowbias[r], zero col if colidx[cN]<0
template <int EPI>
__device__ __forceinline__ void gemm_core(
    const f16* __restrict__ A, const f16* __restrict__ B,
    const float* __restrict__ rowbias, const int* __restrict__ colidx,
    f16* __restrict__ C, int N, int K, int m0, int n0,
    f16* __restrict__ smA, f16* __restrict__ smB) {  // each 2*8192 f16
  int tid = threadIdx.x;
  int lane = tid & 63, w = tid >> 6;
  int wr = w >> 1, wc = w & 1;
  int l15 = lane & 15, lhi = lane >> 4;
  const f16* Ab = A + (size_t)m0 * K;
  const f16* Bb = B + (size_t)n0 * K;

  f32x4 acc[4][4];
  f32x4 z4 = {0.f, 0.f, 0.f, 0.f};
#pragma unroll
  for (int i = 0; i < 4; ++i)
#pragma unroll
    for (int j = 0; j < 4; ++j) acc[i][j] = z4;

  f16x8 ra[4], rb[4];
#pragma unroll
  for (int p = 0; p < 4; ++p) {
    int e = p * 2048 + tid * 8;
    int row = e >> 6, c8 = (e & 63) >> 3;
    ra[p] = *(const f16x8*)(Ab + (size_t)row * K + c8 * 8);
    rb[p] = *(const f16x8*)(Bb + (size_t)row * K + c8 * 8);
  }
#pragma unroll
  for (int p = 0; p < 4; ++p) {
    int e = p * 2048 + tid * 8;
    int row = e >> 6, c8 = (e & 63) >> 3;
    int off = row * 64 + ((c8 ^ (row & 7)) << 3);
    *(f16x8*)(&smA[off]) = ra[p];
    *(f16x8*)(&smB[off]) = rb[p];
  }

  int nk = K >> 6;
  for (int kt = 0; kt < nk; ++kt) {
    int cur = kt & 1;
    bool pre = (kt + 1 < nk);
    __syncthreads();
    if (pre) {
      const f16* An = Ab + (kt + 1) * 64;
      const f16* Bn = Bb + (kt + 1) * 64;
#pragma unroll
      for (int p = 0; p < 4; ++p) {
        int e = p * 2048 + tid * 8;
        int row = e >> 6, c8 = (e & 63) >> 3;
        ra[p] = *(const f16x8*)(An + (size_t)row * K + c8 * 8);
        rb[p] = *(const f16x8*)(Bn + (size_t)row * K + c8 * 8);
      }
    }
    const f16* As = smA + cur * 8192;
    const f16* Bs = smB + cur * 8192;
    __builtin_amdgcn_s_setprio(1);
#pragma unroll
    for (int kk = 0; kk < 2; ++kk) {
      int c8 = kk * 4 + lhi;
      f16x8 af[4], bf[4];
#pragma unroll
      for (int mi = 0; mi < 4; ++mi) {
        int r = wr * 64 + mi * 16 + l15;
        af[mi] = *(const f16x8*)(As + r * 64 + ((c8 ^ (r & 7)) << 3));
      }
#pragma unroll
      for (int ni = 0; ni < 4; ++ni) {
        int r = wc * 64 + ni * 16 + l15;
        bf[ni] = *(const f16x8*)(Bs + r * 64 + ((c8 ^ (r & 7)) << 3));
      }
#pragma unroll
      for (int mi = 0; mi < 4; ++mi)
#pragma unroll
        for (int ni = 0; ni < 4; ++ni)
          acc[mi][ni] = __builtin_amdgcn_mfma_f32_16x16x32_f16(af[mi], bf[ni], acc[mi][ni], 0, 0, 0);
    }
    __builtin_amdgcn_s_setprio(0);
    if (pre) {
#pragma unroll
      for (int p = 0; p < 4; ++p) {
        int e = p * 2048 + tid * 8;
        int row = e >> 6, c8 = (e & 63) >> 3;
        int off = (cur ^ 1) * 8192 + row * 64 + ((c8 ^ (row & 7)) << 3);
        *(f16x8*)(&smA[off]) = ra[p];
        *(f16x8*)(&smB[off]) = rb[p];
      }
    }
  }

  // epilogue: C/D layout col=lane&15, row=(lane>>4)*4+reg  [learn_hip m89]
#pragma unroll
  for (int mi = 0; mi < 4; ++mi) {
#pragma unroll
    for (int j = 0; j < 4; ++j) {
      int r = m0 + wr * 64 + mi * 16 + lhi * 4 + j;
      float rbv = (EPI == 3) ? rowbias[r] : 0.f;
#pragma unroll
      for (int ni = 0; ni < 4; ++ni) {
        int cN = n0 + wc * 64 + ni * 16 + l15;
        float v = acc[mi][ni][j];
        if (EPI == 3) { v += rbv; if (colidx[cN] < 0) v = 0.f; }
        C[(size_t)r * N + cN] = (f16)v;
      }
    }
  }
}

__global__ __launch_bounds__(256) void gemm_f16(const f16* __restrict__ A,
                                                const f16* __restrict__ B,
                                                f16* __restrict__ C, int N, int K) {
  __shared__ __align__(16) f16 sA[2 * 8192], sB[2 * 8192];
  gemm_core<0>(A, B, nullptr, nullptr, C, N, K, blockIdx.y * 128, blockIdx.x * 128, sA, sB);
}

__global__ __launch_bounds__(256) void gemm_dual(const f16* __restrict__ A0,
                                                 const f16* __restrict__ A1,
                                                 const f16* __restrict__ B,
                                                 f16* __restrict__ C0,
                                                 f16* __restrict__ C1, int N, int K) {
  __shared__ __align__(16) f16 sA[2 * 8192], sB[2 * 8192];
  const f16* A = blockIdx.z ? A1 : A0;
  f16* C = blockIdx.z ? C1 : C0;
  gemm_core<0>(A, B, nullptr, nullptr, C, N, K, blockIdx.y * 128, blockIdx.x * 128, sA, sB);
}

__global__ __launch_bounds__(256) void gemm_ewot(const f16* __restrict__ A,
                                                 const f16* __restrict__ B,
                                                 const float* __restrict__ rowbias,
                                                 const int* __restrict__ colidx,
                                                 f16* __restrict__ C, int N, int K) {
  __shared__ __align__(16) f16 sA[2 * 8192], sB[2 * 8192];
  gemm_core<3>(A, B, rowbias, colidx, C, N, K, blockIdx.y * 128, blockIdx.x * 128, sA, sB);
}

// ---------------- fused attention v2 ----------------
// 1D grid 256: b = id&15 (XCD affinity: id%8 == b%8), lt = id>>4.
// 4 waves, 64 Q-rows/block, full 256 entities.
// phase1: S = query(f32->f16) @ Tp^T (K=1024), reg-prefetched pipeline
// phase2: wave-parallel softmax (+cvec, -1e5 mask)
// phase3: O16 = (P*1/32) @ EWot^T (K=256), reg-prefetched, f16 out
__global__ __launch_bounds__(256, 2) void attn2(
    const float* __restrict__ query, const f16* __restrict__ Tp,
    const f16* __restrict__ EWot, const float* __restrict__ cvec,
    const int* __restrict__ idx, f16* __restrict__ O16) {
  __shared__ __align__(16) char pool[65536];
  f16* smB = (f16*)pool;                 // 256x64 swz (phases 1&3)
  f16* smP = (f16*)(pool + 32768);       // 64x256 swz (phases 2&3)
  f16* smQ = (f16*)(pool + 32768);       // 64x64 swz (phase 1 only, aliases smP)
  int id = blockIdx.x;
  int b = id & 15, lt = id >> 4;
  int tid = threadIdx.x, lane = tid & 63, w = tid >> 6;
  int l15 = lane & 15, lhi = lane >> 4;
  const float* Qb = query + (size_t)(b * 1024 + lt * 64) * DM;
  const f16* Tb = Tp + (size_t)b * NBE * DM;

  f32x4 z4 = {0.f, 0.f, 0.f, 0.f};
  f32x4 accs[16];
#pragma unroll
  for (int i = 0; i < 16; ++i) accs[i] = z4;

  float4 rq[4];
  f16x8 rb[8];
  int qrow = tid >> 2, qc0 = (tid & 3) * 16;  // Q stage: 16 f32/thread

  // prefetch tile 0
#pragma unroll
  for (int q = 0; q < 4; ++q)
    rq[q] = *(const float4*)(Qb + (size_t)qrow * DM + qc0 + q * 4);
#pragma unroll
  for (int p = 0; p < 8; ++p) {
    int e = p * 2048 + tid * 8;
    int row = e >> 6, c8 = (e & 63) >> 3;
    rb[p] = *(const f16x8*)(Tb + (size_t)row * DM + c8 * 8);
  }

  // ---- phase 1 ----
  for (int kt = 0; kt < 16; ++kt) {
    __syncthreads();
    {  // store Q (f32->f16) swizzled
      f16x8 h0, h1;
      h0[0] = (f16)rq[0].x; h0[1] = (f16)rq[0].y; h0[2] = (f16)rq[0].z; h0[3] = (f16)rq[0].w;
      h0[4] = (f16)rq[1].x; h0[5] = (f16)rq[1].y; h0[6] = (f16)rq[1].z; h0[7] = (f16)rq[1].w;
      h1[0] = (f16)rq[2].x; h1[1] = (f16)rq[2].y; h1[2] = (f16)rq[2].z; h1[3] = (f16)rq[2].w;
      h1[4] = (f16)rq[3].x; h1[5] = (f16)rq[3].y; h1[6] = (f16)rq[3].z; h1[7] = (f16)rq[3].w;
      int c8a = qc0 >> 3;
      *(f16x8*)(smQ + qrow * 64 + (((c8a    ) ^ (qrow & 7)) << 3)) = h0;
      *(f16x8*)(smQ + qrow * 64 + (((c8a + 1) ^ (qrow & 7)) << 3)) = h1;
    }
#pragma unroll
    for (int p = 0; p < 8; ++p) {
      int e = p * 2048 + tid * 8;
      int row = e >> 6, c8 = (e & 63) >> 3;
      *(f16x8*)(smB + row * 64 + ((c8 ^ (row & 7)) << 3)) = rb[p];
    }
    __syncthreads();
    if (kt < 15) {
#pragma unroll
      for (int q = 0; q < 4; ++q)
        rq[q] = *(const float4*)(Qb + (size_t)qrow * DM + (kt + 1) * 64 + qc0 + q * 4);
#pragma unroll
      for (int p = 0; p < 8; ++p) {
        int e = p * 2048 + tid * 8;
        int row = e >> 6, c8 = (e & 63) >> 3;
        rb[p] = *(const f16x8*)(Tb + (size_t)row * DM + (kt + 1) * 64 + c8 * 8);
      }
    }
    __builtin_amdgcn_s_setprio(1);
#pragma unroll
    for (int kk = 0; kk < 2; ++kk) {
      int c8 = kk * 4 + lhi;
      int qr = w * 16 + l15;
      f16x8 aq = *(const f16x8*)(smQ + qr * 64 + ((c8 ^ (qr & 7)) << 3));
#pragma unroll
      for (int ni = 0; ni < 16; ++ni) {
        int er = ni * 16 + l15;
        f16x8 bb = *(const f16x8*)(smB + er * 64 + ((c8 ^ (er & 7)) << 3));
        accs[ni] = __builtin_amdgcn_mfma_f32_16x16x32_f16(aq, bb, accs[ni], 0, 0, 0);
      }
    }
    __builtin_amdgcn_s_setprio(0);
  }

  // prefetch EWot (dc=0, ks=0) — overlaps softmax
  const f16* Eb = EWot + (size_t)b * NBE;  // row stride 4096
#pragma unroll
  for (int p = 0; p < 8; ++p) {
    int e = p * 2048 + tid * 8;
    int row = e >> 6, c8 = (e & 63) >> 3;
    rb[p] = *(const f16x8*)(Eb + (size_t)row * 4096 + c8 * 8);
  }
  __syncthreads();  // all phase-1 reads of smQ done before smP writes

  // ---- phase 2: softmax ----
  float cv[16];
#pragma unroll
  for (int ni = 0; ni < 16; ++ni) {
    int slot = b * NBE + ni * 16 + l15;
    cv[ni] = cvec[slot] + ((idx[slot] < 0) ? -100000.0f : 0.0f);
  }
#pragma unroll
  for (int j = 0; j < 4; ++j) {
    float mx = -3.0e38f;
#pragma unroll
    for (int ni = 0; ni < 16; ++ni) mx = fmaxf(mx, accs[ni][j] + cv[ni]);
    mx = fmaxf(mx, __shfl_xor(mx, 1));
    mx = fmaxf(mx, __shfl_xor(mx, 2));
    mx = fmaxf(mx, __shfl_xor(mx, 4));
    mx = fmaxf(mx, __shfl_xor(mx, 8));
    float sum = 0.f;
    float pv[16];
#pragma unroll
    for (int ni = 0; ni < 16; ++ni) { pv[ni] = __expf(accs[ni][j] + cv[ni] - mx); sum += pv[ni]; }
    sum += __shfl_xor(sum, 1);
    sum += __shfl_xor(sum, 2);
    sum += __shfl_xor(sum, 4);
    sum += __shfl_xor(sum, 8);
    float inv = 1.0f / sum;
    int r = w * 16 + lhi * 4 + j;
#pragma unroll
    for (int ni = 0; ni < 16; ++ni) {
      int col = ni * 16 + l15;
      int cc8 = col >> 3;
      smP[r * 256 + ((cc8 ^ (r & 7)) << 3) + (col & 7)] = (f16)(pv[ni] * inv);
    }
  }

  // ---- phase 3: O = (P/32) @ EWot^T ----
  f16* Ob = O16 + (size_t)(b * 1024 + lt * 64) * DM;
  for (int dc = 0; dc < 4; ++dc) {
    f32x4 accv[16];
#pragma unroll
    for (int i = 0; i < 16; ++i) accv[i] = z4;
    for (int ks = 0; ks < 4; ++ks) {
      __syncthreads();
#pragma unroll
      for (int p = 0; p < 8; ++p) {
        int e = p * 2048 + tid * 8;
        int row = e >> 6, c8 = (e & 63) >> 3;
        *(f16x8*)(smB + row * 64 + ((c8 ^ (row & 7)) << 3)) = rb[p];
      }
      __syncthreads();
      int nxt = dc * 4 + ks + 1;
      if (nxt < 16) {
        int ndc = nxt >> 2, nks = nxt & 3;
#pragma unroll
        for (int p = 0; p < 8; ++p) {
          int e = p * 2048 + tid * 8;
          int row = e >> 6, c8 = (e & 63) >> 3;
          rb[p] = *(const f16x8*)(Eb + (size_t)(ndc * 256 + row) * 4096 + nks * 64 + c8 * 8);
        }
      }
      __builtin_amdgcn_s_setprio(1);
#pragma unroll
      for (int kk = 0; kk < 2; ++kk) {
        int pc8 = ks * 8 + kk * 4 + lhi;
        int qr = w * 16 + l15;
        f16x8 ap = *(const f16x8*)(smP + qr * 256 + ((pc8 ^ (qr & 7)) << 3));
        int c8 = kk * 4 + lhi;
#pragma unroll
        for (int ni = 0; ni < 16; ++ni) {
          int er = ni * 16 + l15;
          f16x8 bv = *(const f16x8*)(smB + er * 64 + ((c8 ^ (er & 7)) << 3));
          accv[ni] = __builtin_amdgcn_mfma_f32_16x16x32_f16(ap, bv, accv[ni], 0, 0, 0);
        }
      }
      __builtin_amdgcn_s_setprio(0);
    }
#pragma unroll
    for (int ni = 0; ni < 16; ++ni) {
#pragma unroll
      for (int j = 0; j < 4; ++j) {
        int r = w * 16 + lhi * 4 + j;
        int col = dc * 256 + ni * 16 + l15;
        Ob[(size_t)r * DM + col] = (f16)(accv[ni][j] * 0.03125f);
      }
    }
  }
}

// ---------------- LayerNorm: out = LN(O16 + bo) * g + b ----------------
__global__ __launch_bounds__(256) void ln_f16(const f16* __restrict__ X,
                                              const float* __restrict__ bo,
                                              const float* __restrict__ g,
                                              const float* __restrict__ bta,
                                              float* __restrict__ out) {
  size_t row = blockIdx.x;
  const f16* x = X + row * DM;
  int tid = threadIdx.x;
  f16x4 h = *(const f16x4*)(x + tid * 4);
  float4 bo4 = *(const float4*)(bo + tid * 4);
  float4 v;
  v.x = (float)h[0] + bo4.x; v.y = (float)h[1] + bo4.y;
  v.z = (float)h[2] + bo4.z; v.w = (float)h[3] + bo4.w;
  float s = v.x + v.y + v.z + v.w;
  float q = v.x * v.x + v.y * v.y + v.z * v.z + v.w * v.w;
#pragma unroll
  for (int d = 1; d < 64; d <<= 1) { s += __shfl_xor(s, d); q += __shfl_xor(q, d); }
  __shared__ float ss[4], qq[4];
  int w = tid >> 6, lane = tid & 63;
  if (lane == 0) { ss[w] = s; qq[w] = q; }
  __syncthreads();
  s = ss[0] + ss[1] + ss[2] + ss[3];
  q = qq[0] + qq[1] + qq[2] + qq[3];
  float mu = s * (1.0f / DM);
  float var = q * (1.0f / DM) - mu * mu;
  float rs = rsqrtf(var + 1e-5f);
  float4 gg = *(const float4*)(g + tid * 4);
  float4 bb = *(const float4*)(bta + tid * 4);
  float4 o;
  o.x = (v.x - mu) * rs * gg.x + bb.x;
  o.y = (v.y - mu) * rs * gg.y + bb.y;
  o.z = (v.z - mu) * rs * gg.z + bb.z;
  o.w = (v.w - mu) * rs * gg.w + bb.w;
  *(float4*)(out + row * DM + tid * 4) = o;
}

extern "C" void kernel_launch(void* const* d_in, const int* in_sizes, int n_in,
                              void* d_out, int out_size, void* d_ws, size_t ws_size,
                              hipStream_t stream) {
  const float* query   = (const float*)d_in[0];
  const float* ent_emb = (const float*)d_in[1];
  const int*   idx     = (const int*)d_in[2];
  const float* WQ_w = (const float*)d_in[4];
  const float* WQ_b = (const float*)d_in[5];
  const float* WK_w = (const float*)d_in[6];
  const float* WK_b = (const float*)d_in[7];
  const float* WO_w = (const float*)d_in[8];
  const float* WO_b = (const float*)d_in[9];
  const float* ln_g = (const float*)d_in[10];
  const float* ln_b = (const float*)d_in[11];
  float* out = (float*)d_out;

  char* p = (char*)d_ws;
  f16* Egh  = (f16*)p;  p += (size_t)4096 * 1024 * 2;        // 8MB
  f16* WQt  = (f16*)p;  p += (size_t)1024 * 1024 * 2;
  f16* WKt  = (f16*)p;  p += (size_t)1024 * 1024 * 2;
  f16* WOr  = (f16*)p;  p += (size_t)1024 * 1024 * 2;
  f16* G    = (f16*)p;  p += (size_t)1024 * 1024 * 2;
  f16* H    = (f16*)p;  p += (size_t)1024 * 1024 * 2;
  f16* Tp   = (f16*)p;  p += (size_t)4096 * 1024 * 2;        // 8MB
  f16* EWot = (f16*)p;  p += (size_t)1024 * 4096 * 2;        // 8MB
  f16* O16  = (f16*)p;  p += (size_t)16384 * 1024 * 2;       // 32MB
  float* u    = (float*)p; p += 1025 * 4;
  float* wobk = (float*)p; p += 1024 * 4;
  float* cvec = (float*)p; p += 4096 * 4;

  tr2<<<dim3(16, 16, 2), 256, 0, stream>>>(WQ_w, WK_w, WQt, WKt);
  conv_f32_f16<<<1024, 256, 0, stream>>>(WO_w, WOr, 1024 * 1024);
  gather_f16<<<4096, 256, 0, stream>>>(ent_emb, idx, Egh);
  coldot<<<5, 256, 0, stream>>>(WK_w, WQ_b, WK_b, u);
  rowdot<<<256, 256, 0, stream>>>(WO_w, WK_b, wobk);
  // G = WQ^T WK ; H = WO WK (dual launch, shared B=WKt)
  gemm_dual<<<dim3(8, 8, 2), 256, 0, stream>>>(WQt, WOr, WKt, G, H, 1024, 1024);
  cvec_k<<<1024, 256, 0, stream>>>(Egh, u, cvec);
  // Tp = Eg @ G^T
  gemm_f16<<<dim3(8, 32), 256, 0, stream>>>(Egh, G, Tp, 1024, 1024);
  // EWot[d, n] = H[d,:].Eg[n,:] + wobk[d], zeroed for masked n
  gemm_ewot<<<dim3(32, 8), 256, 0, stream>>>(H, Egh, wobk, idx, EWot, 4096, 1024);
  // fused attention -> O16 (f16, pre-bias)
  attn2<<<256, 256, 0, stream>>>(query, Tp, EWot, cvec, idx, O16);
  // out = LN(O16 + bo)
  ln_f16<<<16384, 256, 0, stream>>>(O16, WO_b, ln_g, ln_b, out);
}

// Round 3
// 307.977 us; speedup vs baseline: 1.2319x; 1.0615x over previous
//
#include <hip/hip_runtime.h>
#include <hip/hip_bf16.h>
#include <cstdint>
#include <cstddef>

typedef _Float16 f16;
typedef _Float16 f16x8 __attribute__((ext_vector_type(8)));
typedef _Float16 f16x4 __attribute__((ext_vector_type(4)));
typedef float    f32x4 __attribute__((ext_vector_type(4)));

#define DM 1024   // d_model
#define NBE 256   // entities per batch row

// ================= prep: fused conv(WO) + transpose(WQ,WK) + gather + coldot + rowdot =====
__global__ __launch_bounds__(256) void prep(
    const float* __restrict__ WO_w, f16* __restrict__ WOr,
    const float* __restrict__ WQ_w, const float* __restrict__ WK_w,
    f16* __restrict__ WQt, f16* __restrict__ WKt,
    const float* __restrict__ ent_emb, const int* __restrict__ idx,
    f16* __restrict__ Egh,
    const float* __restrict__ WQ_b, const float* __restrict__ WK_b,
    float* __restrict__ u, float* __restrict__ wobk) {
  __shared__ float ts[64][65];
  __shared__ float sm4[4];
  int blk = blockIdx.x, tid = threadIdx.x;
  if (blk < 1024) {                      // WO_w f32 -> f16
    int i = (blk * 256 + tid) * 4;
    float4 v = *(const float4*)(WO_w + i);
    f16x4 o; o.x = (f16)v.x; o.y = (f16)v.y; o.z = (f16)v.z; o.w = (f16)v.w;
    *(f16x4*)(WOr + i) = o;
  } else if (blk < 1536) {               // transpose WQ, WK -> f16
    int t = blk - 1024;
    const float* in = (t >> 8) ? WK_w : WQ_w;
    f16* out = (t >> 8) ? WKt : WQt;
    int bi = ((t >> 4) & 15) * 64, bj = (t & 15) * 64;
    int tx = tid & 63, ty = tid >> 6;
#pragma unroll
    for (int k = 0; k < 16; ++k) {
      int r = ty * 16 + k;
      ts[r][tx] = in[(size_t)(bi + r) * DM + bj + tx];
    }
    __syncthreads();
#pragma unroll
    for (int k = 0; k < 16; ++k) {
      int r = ty * 16 + k;
      out[(size_t)(bj + r) * DM + bi + tx] = (f16)ts[tx][r];
    }
  } else if (blk < 5632) {               // gather entities -> f16 (zero masked)
    int slot = blk - 1536;
    int e = idx[slot];
    int c = tid * 4;
    f16x4 o;
    if (e < 0) {
      o.x = (f16)0.f; o.y = (f16)0.f; o.z = (f16)0.f; o.w = (f16)0.f;
    } else {
      float4 v = *(const float4*)(ent_emb + (size_t)e * DM + c);
      o.x = (f16)v.x; o.y = (f16)v.y; o.z = (f16)v.z; o.w = (f16)v.w;
    }
    *(f16x4*)(Egh + (size_t)slot * DM + c) = o;
  } else if (blk < 5637) {               // u[k] = bq.WK[:,k]; u[1024] = bk.bq
    int t = blk - 5632;
    if (t < 4) {
      int k = t * 256 + tid;
      float s = 0.f;
      for (int d = 0; d < 1024; ++d) s += WQ_b[d] * WK_w[(size_t)d * 1024 + k];
      u[k] = s;
    } else {
      float s = 0.f;
      for (int i = tid; i < 1024; i += 256) s += WK_b[i] * WQ_b[i];
#pragma unroll
      for (int d = 1; d < 64; d <<= 1) s += __shfl_xor(s, d);
      int w = tid >> 6;
      if ((tid & 63) == 0) sm4[w] = s;
      __syncthreads();
      if (tid == 0) u[1024] = sm4[0] + sm4[1] + sm4[2] + sm4[3];
    }
  } else {                               // wobk[r] = WO[r,:].bk
    int w = tid >> 6, lane = tid & 63;
    int r = (blk - 5637) * 4 + w;
    const float* a = WO_w + (size_t)r * 1024;
    float s = 0.f;
#pragma unroll
    for (int i = 0; i < 16; ++i) s += a[lane + i * 64] * WK_b[lane + i * 64];
#pragma unroll
    for (int d = 1; d < 64; d <<= 1) s += __shfl_xor(s, d);
    if (lane == 0) wobk[r] = s;
  }
}

// ================= generic TN GEMM core: C[M,N] = A[M,K] @ B[N,K]^T =================
// EPI 0: f16 out, plain.  EPI 3: f16 out, + rowbias[r], zero col if colidx[cN]<0
template <int EPI>
__device__ __forceinline__ void gemm_core(
    const f16* __restrict__ A, const f16* __restrict__ B,
    const float* __restrict__ rowbias, const int* __restrict__ colidx,
    f16* __restrict__ C, int N, int K, int m0, int n0,
    f16* __restrict__ smA, f16* __restrict__ smB) {
  int tid = threadIdx.x;
  int lane = tid & 63, w = tid >> 6;
  int wr = w >> 1, wc = w & 1;
  int l15 = lane & 15, lhi = lane >> 4;
  const f16* Ab = A + (size_t)m0 * K;
  const f16* Bb = B + (size_t)n0 * K;

  f32x4 acc[4][4];
  f32x4 z4 = {0.f, 0.f, 0.f, 0.f};
#pragma unroll
  for (int i = 0; i < 4; ++i)
#pragma unroll
    for (int j = 0; j < 4; ++j) acc[i][j] = z4;

  f16x8 ra[4], rb[4];
#pragma unroll
  for (int p = 0; p < 4; ++p) {
    int e = p * 2048 + tid * 8;
    int row = e >> 6, c8 = (e & 63) >> 3;
    ra[p] = *(const f16x8*)(Ab + (size_t)row * K + c8 * 8);
    rb[p] = *(const f16x8*)(Bb + (size_t)row * K + c8 * 8);
  }
#pragma unroll
  for (int p = 0; p < 4; ++p) {
    int e = p * 2048 + tid * 8;
    int row = e >> 6, c8 = (e & 63) >> 3;
    int off = row * 64 + ((c8 ^ (row & 7)) << 3);
    *(f16x8*)(&smA[off]) = ra[p];
    *(f16x8*)(&smB[off]) = rb[p];
  }

  int nk = K >> 6;
  for (int kt = 0; kt < nk; ++kt) {
    int cur = kt & 1;
    bool pre = (kt + 1 < nk);
    __syncthreads();
    if (pre) {
      const f16* An = Ab + (kt + 1) * 64;
      const f16* Bn = Bb + (kt + 1) * 64;
#pragma unroll
      for (int p = 0; p < 4; ++p) {
        int e = p * 2048 + tid * 8;
        int row = e >> 6, c8 = (e & 63) >> 3;
        ra[p] = *(const f16x8*)(An + (size_t)row * K + c8 * 8);
        rb[p] = *(const f16x8*)(Bn + (size_t)row * K + c8 * 8);
      }
    }
    const f16* As = smA + cur * 8192;
    const f16* Bs = smB + cur * 8192;
    __builtin_amdgcn_s_setprio(1);
#pragma unroll
    for (int kk = 0; kk < 2; ++kk) {
      int c8 = kk * 4 + lhi;
      f16x8 af[4], bf[4];
#pragma unroll
      for (int mi = 0; mi < 4; ++mi) {
        int r = wr * 64 + mi * 16 + l15;
        af[mi] = *(const f16x8*)(As + r * 64 + ((c8 ^ (r & 7)) << 3));
      }
#pragma unroll
      for (int ni = 0; ni < 4; ++ni) {
        int r = wc * 64 + ni * 16 + l15;
        bf[ni] = *(const f16x8*)(Bs + r * 64 + ((c8 ^ (r & 7)) << 3));
      }
#pragma unroll
      for (int mi = 0; mi < 4; ++mi)
#pragma unroll
        for (int ni = 0; ni < 4; ++ni)
          acc[mi][ni] = __builtin_amdgcn_mfma_f32_16x16x32_f16(af[mi], bf[ni], acc[mi][ni], 0, 0, 0);
    }
    __builtin_amdgcn_s_setprio(0);
    if (pre) {
#pragma unroll
      for (int p = 0; p < 4; ++p) {
        int e = p * 2048 + tid * 8;
        int row = e >> 6, c8 = (e & 63) >> 3;
        int off = (cur ^ 1) * 8192 + row * 64 + ((c8 ^ (row & 7)) << 3);
        *(f16x8*)(&smA[off]) = ra[p];
        *(f16x8*)(&smB[off]) = rb[p];
      }
    }
  }

#pragma unroll
  for (int mi = 0; mi < 4; ++mi) {
#pragma unroll
    for (int j = 0; j < 4; ++j) {
      int r = m0 + wr * 64 + mi * 16 + lhi * 4 + j;
      float rbv = (EPI == 3) ? rowbias[r] : 0.f;
#pragma unroll
      for (int ni = 0; ni < 4; ++ni) {
        int cN = n0 + wc * 64 + ni * 16 + l15;
        float v = acc[mi][ni][j];
        if (EPI == 3) { v += rbv; if (colidx[cN] < 0) v = 0.f; }
        C[(size_t)r * N + cN] = (f16)v;
      }
    }
  }
}

// G = WQ^T WK ; H = WO WK (shared B operand)
__global__ __launch_bounds__(256) void gemm_dual(const f16* __restrict__ A0,
                                                 const f16* __restrict__ A1,
                                                 const f16* __restrict__ B,
                                                 f16* __restrict__ C0,
                                                 f16* __restrict__ C1, int N, int K) {
  __shared__ __align__(16) f16 sA[2 * 8192], sB[2 * 8192];
  const f16* A = blockIdx.z ? A1 : A0;
  f16* C = blockIdx.z ? C1 : C0;
  gemm_core<0>(A, B, nullptr, nullptr, C, N, K, blockIdx.y * 128, blockIdx.x * 128, sA, sB);
}

// Tp = Eg @ G^T (256 blocks) ; EWot = H @ Eg^T + wobk, masked (256 blocks) ; cvec (1024 blocks)
__global__ __launch_bounds__(256) void gemm_pair(
    const f16* __restrict__ Egh, const f16* __restrict__ G, const f16* __restrict__ H,
    const float* __restrict__ wobk, const int* __restrict__ idx,
    const float* __restrict__ u,
    f16* __restrict__ Tp, f16* __restrict__ EWot, float* __restrict__ cvec) {
  __shared__ __align__(16) f16 sA[2 * 8192], sB[2 * 8192];
  int blk = blockIdx.x;
  if (blk < 256) {
    gemm_core<0>(Egh, G, nullptr, nullptr, Tp, 1024, 1024, (blk >> 3) * 128, (blk & 7) * 128, sA, sB);
  } else if (blk < 512) {
    int t = blk - 256;
    gemm_core<3>(H, Egh, wobk, idx, EWot, 4096, 1024, (t >> 5) * 128, (t & 31) * 128, sA, sB);
  } else {
    int t = blk - 512;
    int w = threadIdx.x >> 6, lane = threadIdx.x & 63;
    int n = t * 4 + w;
    const f16* e = Egh + (size_t)n * 1024;
    float s = 0.f;
#pragma unroll
    for (int i = 0; i < 16; ++i) { int k = lane + i * 64; s += (float)e[k] * u[k]; }
#pragma unroll
    for (int d = 1; d < 64; d <<= 1) s += __shfl_xor(s, d);
    if (lane == 0)
      cvec[n] = s + u[1024] + ((idx[n] < 0) ? -100000.0f : 0.0f);
  }
}

// ================= fused attention v3 =================
// grid 512: b = id&15 (XCD affinity), lt = id>>4 (32 tiles of 32 Q-rows).
// 4 waves 2x2: wq = row half (16 rows), wc = entity half (128 cols).
// phase1: S = query(f32->f16) @ Tp^T (K=1024); phase2: cross-wave softmax (mask+cvec
// prefolded, 1/32 folded into normalizer); phase3: O16 = P @ EWot^T (K=256).
__global__ __launch_bounds__(256, 2) void attn3(
    const float* __restrict__ query, const f16* __restrict__ Tp,
    const f16* __restrict__ EWot, const float* __restrict__ cvec,
    f16* __restrict__ O16) {
  __shared__ __align__(16) char pool[49152];
  f16* smB = (f16*)pool;                 // 256x64 swz
  f16* smP = (f16*)(pool + 32768);       // 32x256 swz
  f16* smQ = (f16*)(pool + 32768);       // 32x64 swz (phase1 alias)
  __shared__ float smMax[64], smSum[64];
  int id = blockIdx.x;
  int b = id & 15, lt = id >> 4;
  int tid = threadIdx.x, lane = tid & 63, w = tid >> 6;
  int l15 = lane & 15, lhi = lane >> 4;
  int wq = w >> 1, wc = w & 1;
  const float* Qb = query + (size_t)(b * 1024 + lt * 32) * DM;
  const f16* Tb = Tp + (size_t)b * NBE * DM;

  f32x4 z4 = {0.f, 0.f, 0.f, 0.f};
  f32x4 accs[8];
#pragma unroll
  for (int i = 0; i < 8; ++i) accs[i] = z4;

  float4 rqa, rqb;
  f16x8 rb[8];
  int qrow = tid >> 3, qc0 = (tid & 7) * 8;   // Q stage: 8 f32/thread

  rqa = *(const float4*)(Qb + (size_t)qrow * DM + qc0);
  rqb = *(const float4*)(Qb + (size_t)qrow * DM + qc0 + 4);
#pragma unroll
  for (int p = 0; p < 8; ++p) {
    int e = p * 2048 + tid * 8;
    int row = e >> 6, c8 = (e & 63) >> 3;
    rb[p] = *(const f16x8*)(Tb + (size_t)row * DM + c8 * 8);
  }

  // ---- phase 1 ----
  for (int kt = 0; kt < 16; ++kt) {
    __syncthreads();
    {
      f16x8 h;
      h[0] = (f16)rqa.x; h[1] = (f16)rqa.y; h[2] = (f16)rqa.z; h[3] = (f16)rqa.w;
      h[4] = (f16)rqb.x; h[5] = (f16)rqb.y; h[6] = (f16)rqb.z; h[7] = (f16)rqb.w;
      int c8 = qc0 >> 3;
      *(f16x8*)(smQ + qrow * 64 + ((c8 ^ (qrow & 7)) << 3)) = h;
    }
#pragma unroll
    for (int p = 0; p < 8; ++p) {
      int e = p * 2048 + tid * 8;
      int row = e >> 6, c8 = (e & 63) >> 3;
      *(f16x8*)(smB + row * 64 + ((c8 ^ (row & 7)) << 3)) = rb[p];
    }
    __syncthreads();
    if (kt < 15) {
      rqa = *(const float4*)(Qb + (size_t)qrow * DM + (kt + 1) * 64 + qc0);
      rqb = *(const float4*)(Qb + (size_t)qrow * DM + (kt + 1) * 64 + qc0 + 4);
#pragma unroll
      for (int p = 0; p < 8; ++p) {
        int e = p * 2048 + tid * 8;
        int row = e >> 6, c8 = (e & 63) >> 3;
        rb[p] = *(const f16x8*)(Tb + (size_t)row * DM + (kt + 1) * 64 + c8 * 8);
      }
    }
    __builtin_amdgcn_s_setprio(1);
#pragma unroll
    for (int kk = 0; kk < 2; ++kk) {
      int c8 = kk * 4 + lhi;
      int qr = wq * 16 + l15;
      f16x8 aq = *(const f16x8*)(smQ + qr * 64 + ((c8 ^ (qr & 7)) << 3));
#pragma unroll
      for (int ni = 0; ni < 8; ++ni) {
        int er = wc * 128 + ni * 16 + l15;
        f16x8 bb = *(const f16x8*)(smB + er * 64 + ((c8 ^ (er & 7)) << 3));
        accs[ni] = __builtin_amdgcn_mfma_f32_16x16x32_f16(aq, bb, accs[ni], 0, 0, 0);
      }
    }
    __builtin_amdgcn_s_setprio(0);
  }

  // prefetch EWot tile (dc=0, ks=0) — overlaps softmax
  const f16* Eb = EWot + (size_t)b * NBE;  // row stride 4096
#pragma unroll
  for (int p = 0; p < 8; ++p) {
    int e = p * 2048 + tid * 8;
    int row = e >> 6, c8 = (e & 63) >> 3;
    rb[p] = *(const f16x8*)(Eb + (size_t)row * 4096 + c8 * 8);
  }

  // ---- phase 2: softmax with cross-wave (wc) combine ----
  float cv[8];
#pragma unroll
  for (int ni = 0; ni < 8; ++ni)
    cv[ni] = cvec[b * NBE + wc * 128 + ni * 16 + l15];
  int rbase = wq * 16 + lhi * 4;
  float mxl[4], sml[4];
#pragma unroll
  for (int j = 0; j < 4; ++j) {
    float m = -3.0e38f;
#pragma unroll
    for (int ni = 0; ni < 8; ++ni) m = fmaxf(m, accs[ni][j] + cv[ni]);
    m = fmaxf(m, __shfl_xor(m, 1));
    m = fmaxf(m, __shfl_xor(m, 2));
    m = fmaxf(m, __shfl_xor(m, 4));
    m = fmaxf(m, __shfl_xor(m, 8));
    mxl[j] = m;
    if (l15 == 0) smMax[wc * 32 + rbase + j] = m;
  }
  __syncthreads();
#pragma unroll
  for (int j = 0; j < 4; ++j) {
    float fm = fmaxf(mxl[j], smMax[(wc ^ 1) * 32 + rbase + j]);
    float s = 0.f;
#pragma unroll
    for (int ni = 0; ni < 8; ++ni) {
      float e = __expf(accs[ni][j] + cv[ni] - fm);
      accs[ni][j] = e;
      s += e;
    }
    s += __shfl_xor(s, 1);
    s += __shfl_xor(s, 2);
    s += __shfl_xor(s, 4);
    s += __shfl_xor(s, 8);
    sml[j] = s;
    if (l15 == 0) smSum[wc * 32 + rbase + j] = s;
  }
  __syncthreads();
#pragma unroll
  for (int j = 0; j < 4; ++j) {
    float inv = 0.03125f / (sml[j] + smSum[(wc ^ 1) * 32 + rbase + j]);
    int r = rbase + j;
#pragma unroll
    for (int ni = 0; ni < 8; ++ni) {
      int col = wc * 128 + ni * 16 + l15;
      int cc8 = col >> 3;
      smP[r * 256 + ((cc8 ^ (r & 7)) << 3) + (col & 7)] = (f16)(accs[ni][j] * inv);
    }
  }

  // ---- phase 3: O = P @ EWot^T ----
  f16* Ob = O16 + (size_t)(b * 1024 + lt * 32) * DM;
  for (int dc = 0; dc < 4; ++dc) {
    f32x4 accv[8];
#pragma unroll
    for (int i = 0; i < 8; ++i) accv[i] = z4;
    for (int ks = 0; ks < 4; ++ks) {
      __syncthreads();
#pragma unroll
      for (int p = 0; p < 8; ++p) {
        int e = p * 2048 + tid * 8;
        int row = e >> 6, c8 = (e & 63) >> 3;
        *(f16x8*)(smB + row * 64 + ((c8 ^ (row & 7)) << 3)) = rb[p];
      }
      __syncthreads();
      int nxt = dc * 4 + ks + 1;
      if (nxt < 16) {
        int ndc = nxt >> 2, nks = nxt & 3;
#pragma unroll
        for (int p = 0; p < 8; ++p) {
          int e = p * 2048 + tid * 8;
          int row = e >> 6, c8 = (e & 63) >> 3;
          rb[p] = *(const f16x8*)(Eb + (size_t)(ndc * 256 + row) * 4096 + nks * 64 + c8 * 8);
        }
      }
      __builtin_amdgcn_s_setprio(1);
#pragma unroll
      for (int kk = 0; kk < 2; ++kk) {
        int pc8 = ks * 8 + kk * 4 + lhi;
        int qr = wq * 16 + l15;
        f16x8 ap = *(const f16x8*)(smP + qr * 256 + ((pc8 ^ (qr & 7)) << 3));
        int c8 = kk * 4 + lhi;
#pragma unroll
        for (int ni = 0; ni < 8; ++ni) {
          int er = wc * 128 + ni * 16 + l15;
          f16x8 bv = *(const f16x8*)(smB + er * 64 + ((c8 ^ (er & 7)) << 3));
          accv[ni] = __builtin_amdgcn_mfma_f32_16x16x32_f16(ap, bv, accv[ni], 0, 0, 0);
        }
      }
      __builtin_amdgcn_s_setprio(0);
    }
#pragma unroll
    for (int ni = 0; ni < 8; ++ni) {
#pragma unroll
      for (int j = 0; j < 4; ++j) {
        int r = wq * 16 + lhi * 4 + j;
        int col = dc * 256 + wc * 128 + ni * 16 + l15;
        Ob[(size_t)r * DM + col] = (f16)accv[ni][j];
      }
    }
  }
}

// ================= LayerNorm: out = LN(O16 + bo) * g + b =================
__global__ __launch_bounds__(256) void ln_f16(const f16* __restrict__ X,
                                              const float* __restrict__ bo,
                                              const float* __restrict__ g,
                                              const float* __restrict__ bta,
                                              float* __restrict__ out) {
  size_t row = blockIdx.x;
  const f16* x = X + row * DM;
  int tid = threadIdx.x;
  f16x4 h = *(const f16x4*)(x + tid * 4);
  float4 bo4 = *(const float4*)(bo + tid * 4);
  float4 v;
  v.x = (float)h[0] + bo4.x; v.y = (float)h[1] + bo4.y;
  v.z = (float)h[2] + bo4.z; v.w = (float)h[3] + bo4.w;
  float s = v.x + v.y + v.z + v.w;
  float q = v.x * v.x + v.y * v.y + v.z * v.z + v.w * v.w;
#pragma unroll
  for (int d = 1; d < 64; d <<= 1) { s += __shfl_xor(s, d); q += __shfl_xor(q, d); }
  __shared__ float ss[4], qq[4];
  int w = tid >> 6, lane = tid & 63;
  if (lane == 0) { ss[w] = s; qq[w] = q; }
  __syncthreads();
  s = ss[0] + ss[1] + ss[2] + ss[3];
  q = qq[0] + qq[1] + qq[2] + qq[3];
  float mu = s * (1.0f / DM);
  float var = q * (1.0f / DM) - mu * mu;
  float rs = rsqrtf(var + 1e-5f);
  float4 gg = *(const float4*)(g + tid * 4);
  float4 bb = *(const float4*)(bta + tid * 4);
  float4 o;
  o.x = (v.x - mu) * rs * gg.x + bb.x;
  o.y = (v.y - mu) * rs * gg.y + bb.y;
  o.z = (v.z - mu) * rs * gg.z + bb.z;
  o.w = (v.w - mu) * rs * gg.w + bb.w;
  *(float4*)(out + row * DM + tid * 4) = o;
}

extern "C" void kernel_launch(void* const* d_in, const int* in_sizes, int n_in,
                              void* d_out, int out_size, void* d_ws, size_t ws_size,
                              hipStream_t stream) {
  const float* query   = (const float*)d_in[0];
  const float* ent_emb = (const float*)d_in[1];
  const int*   idx     = (const int*)d_in[2];
  const float* WQ_w = (const float*)d_in[4];
  const float* WQ_b = (const float*)d_in[5];
  const float* WK_w = (const float*)d_in[6];
  const float* WK_b = (const float*)d_in[7];
  const float* WO_w = (const float*)d_in[8];
  const float* WO_b = (const float*)d_in[9];
  const float* ln_g = (const float*)d_in[10];
  const float* ln_b = (const float*)d_in[11];
  float* out = (float*)d_out;

  char* p = (char*)d_ws;
  f16* Egh  = (f16*)p;  p += (size_t)4096 * 1024 * 2;        // 8MB
  f16* WQt  = (f16*)p;  p += (size_t)1024 * 1024 * 2;
  f16* WKt  = (f16*)p;  p += (size_t)1024 * 1024 * 2;
  f16* WOr  = (f16*)p;  p += (size_t)1024 * 1024 * 2;
  f16* G    = (f16*)p;  p += (size_t)1024 * 1024 * 2;
  f16* H    = (f16*)p;  p += (size_t)1024 * 1024 * 2;
  f16* Tp   = (f16*)p;  p += (size_t)4096 * 1024 * 2;        // 8MB
  f16* EWot = (f16*)p;  p += (size_t)1024 * 4096 * 2;        // 8MB
  f16* O16  = (f16*)p;  p += (size_t)16384 * 1024 * 2;       // 32MB
  float* u    = (float*)p; p += 1025 * 4;
  float* wobk = (float*)p; p += 1024 * 4;
  float* cvec = (float*)p; p += 4096 * 4;

  // fused prep: conv(WO), tr(WQ,WK), gather, u, wobk
  prep<<<5893, 256, 0, stream>>>(WO_w, WOr, WQ_w, WK_w, WQt, WKt,
                                 ent_emb, idx, Egh, WQ_b, WK_b, u, wobk);
  // G = WQ^T WK ; H = WO WK
  gemm_dual<<<dim3(8, 8, 2), 256, 0, stream>>>(WQt, WOr, WKt, G, H, 1024, 1024);
  // Tp = Eg @ G^T ; EWot = H @ Eg^T + wobk (masked) ; cvec (+mask fold)
  gemm_pair<<<1536, 256, 0, stream>>>(Egh, G, H, wobk, idx, u, Tp, EWot, cvec);
  // fused attention -> O16 (f16, pre-bias, pre-scaled)
  attn3<<<512, 256, 0, stream>>>(query, Tp, EWot, cvec, O16);
  // out = LN(O16 + bo)
  ln_f16<<<16384, 256, 0, stream>>>(O16, WO_b, ln_g, ln_b, out);
}

// Round 4
// 288.803 us; speedup vs baseline: 1.3137x; 1.0664x over previous
//
#include <hip/hip_runtime.h>
#include <hip/hip_bf16.h>
#include <cstdint>
#include <cstddef>

typedef _Float16 f16;
typedef _Float16 f16x8 __attribute__((ext_vector_type(8)));
typedef _Float16 f16x4 __attribute__((ext_vector_type(4)));
typedef float    f32x4 __attribute__((ext_vector_type(4)));

#define DM 1024   // d_model
#define NBE 256   // entities per batch row

// ================= prep: fused conv(WO) + transpose(WQ,WK) + gather + coldot + rowdot =====
__global__ __launch_bounds__(256) void prep(
    const float* __restrict__ WO_w, f16* __restrict__ WOr,
    const float* __restrict__ WQ_w, const float* __restrict__ WK_w,
    f16* __restrict__ WQt, f16* __restrict__ WKt,
    const float* __restrict__ ent_emb, const int* __restrict__ idx,
    f16* __restrict__ Egh,
    const float* __restrict__ WQ_b, const float* __restrict__ WK_b,
    float* __restrict__ u, float* __restrict__ wobk) {
  __shared__ float ts[64][65];
  __shared__ float sm4[4];
  int blk = blockIdx.x, tid = threadIdx.x;
  if (blk < 1024) {                      // WO_w f32 -> f16
    int i = (blk * 256 + tid) * 4;
    float4 v = *(const float4*)(WO_w + i);
    f16x4 o; o.x = (f16)v.x; o.y = (f16)v.y; o.z = (f16)v.z; o.w = (f16)v.w;
    *(f16x4*)(WOr + i) = o;
  } else if (blk < 1536) {               // transpose WQ, WK -> f16
    int t = blk - 1024;
    const float* in = (t >> 8) ? WK_w : WQ_w;
    f16* out = (t >> 8) ? WKt : WQt;
    int bi = ((t >> 4) & 15) * 64, bj = (t & 15) * 64;
    int tx = tid & 63, ty = tid >> 6;
#pragma unroll
    for (int k = 0; k < 16; ++k) {
      int r = ty * 16 + k;
      ts[r][tx] = in[(size_t)(bi + r) * DM + bj + tx];
    }
    __syncthreads();
#pragma unroll
    for (int k = 0; k < 16; ++k) {
      int r = ty * 16 + k;
      out[(size_t)(bj + r) * DM + bi + tx] = (f16)ts[tx][r];
    }
  } else if (blk < 5632) {               // gather entities -> f16 (zero masked)
    int slot = blk - 1536;
    int e = idx[slot];
    int c = tid * 4;
    f16x4 o;
    if (e < 0) {
      o.x = (f16)0.f; o.y = (f16)0.f; o.z = (f16)0.f; o.w = (f16)0.f;
    } else {
      float4 v = *(const float4*)(ent_emb + (size_t)e * DM + c);
      o.x = (f16)v.x; o.y = (f16)v.y; o.z = (f16)v.z; o.w = (f16)v.w;
    }
    *(f16x4*)(Egh + (size_t)slot * DM + c) = o;
  } else if (blk < 5648) {               // u[k] += bq[d0..d0+63] . WK[d0..,k] (atomic)
    int d0 = (blk - 5632) * 64;
    float a0 = 0.f, a1 = 0.f, a2 = 0.f, a3 = 0.f;
    for (int d = 0; d < 64; ++d) {
      float bq = WQ_b[d0 + d];
      const float* row = WK_w + (size_t)(d0 + d) * 1024;
      a0 += bq * row[tid];
      a1 += bq * row[tid + 256];
      a2 += bq * row[tid + 512];
      a3 += bq * row[tid + 768];
    }
    atomicAdd(&u[tid], a0);
    atomicAdd(&u[tid + 256], a1);
    atomicAdd(&u[tid + 512], a2);
    atomicAdd(&u[tid + 768], a3);
  } else if (blk < 5649) {               // u[1024] = bk.bq
    float s = 0.f;
    for (int i = tid; i < 1024; i += 256) s += WK_b[i] * WQ_b[i];
#pragma unroll
    for (int d = 1; d < 64; d <<= 1) s += __shfl_xor(s, d);
    int w = tid >> 6;
    if ((tid & 63) == 0) sm4[w] = s;
    __syncthreads();
    if (tid == 0) u[1024] = sm4[0] + sm4[1] + sm4[2] + sm4[3];
  } else {                               // wobk[r] = WO[r,:].bk
    int w = tid >> 6, lane = tid & 63;
    int r = (blk - 5649) * 4 + w;
    const float* a = WO_w + (size_t)r * 1024;
    float s = 0.f;
#pragma unroll
    for (int i = 0; i < 16; ++i) s += a[lane + i * 64] * WK_b[lane + i * 64];
#pragma unroll
    for (int d = 1; d < 64; d <<= 1) s += __shfl_xor(s, d);
    if (lane == 0) wobk[r] = s;
  }
}

// ================= generic TN GEMM core: C[M,N] = A[M,K] @ B[N,K]^T =================
// EPI 0: f16 out, plain.  EPI 3: f16 out, + rowbias[r], zero col if colidx[cN]<0
template <int EPI>
__device__ __forceinline__ void gemm_core(
    const f16* __restrict__ A, const f16* __restrict__ B,
    const float* __restrict__ rowbias, const int* __restrict__ colidx,
    f16* __restrict__ C, int N, int K, int m0, int n0,
    f16* __restrict__ smA, f16* __restrict__ smB) {
  int tid = threadIdx.x;
  int lane = tid & 63, w = tid >> 6;
  int wr = w >> 1, wc = w & 1;
  int l15 = lane & 15, lhi = lane >> 4;
  const f16* Ab = A + (size_t)m0 * K;
  const f16* Bb = B + (size_t)n0 * K;

  f32x4 acc[4][4];
  f32x4 z4 = {0.f, 0.f, 0.f, 0.f};
#pragma unroll
  for (int i = 0; i < 4; ++i)
#pragma unroll
    for (int j = 0; j < 4; ++j) acc[i][j] = z4;

  f16x8 ra[4], rb[4];
#pragma unroll
  for (int p = 0; p < 4; ++p) {
    int e = p * 2048 + tid * 8;
    int row = e >> 6, c8 = (e & 63) >> 3;
    ra[p] = *(const f16x8*)(Ab + (size_t)row * K + c8 * 8);
    rb[p] = *(const f16x8*)(Bb + (size_t)row * K + c8 * 8);
  }
#pragma unroll
  for (int p = 0; p < 4; ++p) {
    int e = p * 2048 + tid * 8;
    int row = e >> 6, c8 = (e & 63) >> 3;
    int off = row * 64 + ((c8 ^ (row & 7)) << 3);
    *(f16x8*)(&smA[off]) = ra[p];
    *(f16x8*)(&smB[off]) = rb[p];
  }

  int nk = K >> 6;
  for (int kt = 0; kt < nk; ++kt) {
    int cur = kt & 1;
    bool pre = (kt + 1 < nk);
    __syncthreads();
    if (pre) {
      const f16* An = Ab + (kt + 1) * 64;
      const f16* Bn = Bb + (kt + 1) * 64;
#pragma unroll
      for (int p = 0; p < 4; ++p) {
        int e = p * 2048 + tid * 8;
        int row = e >> 6, c8 = (e & 63) >> 3;
        ra[p] = *(const f16x8*)(An + (size_t)row * K + c8 * 8);
        rb[p] = *(const f16x8*)(Bn + (size_t)row * K + c8 * 8);
      }
    }
    const f16* As = smA + cur * 8192;
    const f16* Bs = smB + cur * 8192;
    __builtin_amdgcn_s_setprio(1);
#pragma unroll
    for (int kk = 0; kk < 2; ++kk) {
      int c8 = kk * 4 + lhi;
      f16x8 af[4], bf[4];
#pragma unroll
      for (int mi = 0; mi < 4; ++mi) {
        int r = wr * 64 + mi * 16 + l15;
        af[mi] = *(const f16x8*)(As + r * 64 + ((c8 ^ (r & 7)) << 3));
      }
#pragma unroll
      for (int ni = 0; ni < 4; ++ni) {
        int r = wc * 64 + ni * 16 + l15;
        bf[ni] = *(const f16x8*)(Bs + r * 64 + ((c8 ^ (r & 7)) << 3));
      }
#pragma unroll
      for (int mi = 0; mi < 4; ++mi)
#pragma unroll
        for (int ni = 0; ni < 4; ++ni)
          acc[mi][ni] = __builtin_amdgcn_mfma_f32_16x16x32_f16(af[mi], bf[ni], acc[mi][ni], 0, 0, 0);
    }
    __builtin_amdgcn_s_setprio(0);
    if (pre) {
#pragma unroll
      for (int p = 0; p < 4; ++p) {
        int e = p * 2048 + tid * 8;
        int row = e >> 6, c8 = (e & 63) >> 3;
        int off = (cur ^ 1) * 8192 + row * 64 + ((c8 ^ (row & 7)) << 3);
        *(f16x8*)(&smA[off]) = ra[p];
        *(f16x8*)(&smB[off]) = rb[p];
      }
    }
  }

#pragma unroll
  for (int mi = 0; mi < 4; ++mi) {
#pragma unroll
    for (int j = 0; j < 4; ++j) {
      int r = m0 + wr * 64 + mi * 16 + lhi * 4 + j;
      float rbv = (EPI == 3) ? rowbias[r] : 0.f;
#pragma unroll
      for (int ni = 0; ni < 4; ++ni) {
        int cN = n0 + wc * 64 + ni * 16 + l15;
        float v = acc[mi][ni][j];
        if (EPI == 3) { v += rbv; if (colidx[cN] < 0) v = 0.f; }
        C[(size_t)r * N + cN] = (f16)v;
      }
    }
  }
}

// G = WQ^T WK ; H = WO WK (shared B operand)
__global__ __launch_bounds__(256) void gemm_dual(const f16* __restrict__ A0,
                                                 const f16* __restrict__ A1,
                                                 const f16* __restrict__ B,
                                                 f16* __restrict__ C0,
                                                 f16* __restrict__ C1, int N, int K) {
  __shared__ __align__(16) f16 sA[2 * 8192], sB[2 * 8192];
  const f16* A = blockIdx.z ? A1 : A0;
  f16* C = blockIdx.z ? C1 : C0;
  gemm_core<0>(A, B, nullptr, nullptr, C, N, K, blockIdx.y * 128, blockIdx.x * 128, sA, sB);
}

// Tp = Eg @ G^T (256 blocks) ; EWot = H @ Eg^T + wobk, masked (256 blocks) ; cvec (1024 blocks)
__global__ __launch_bounds__(256) void gemm_pair(
    const f16* __restrict__ Egh, const f16* __restrict__ G, const f16* __restrict__ H,
    const float* __restrict__ wobk, const int* __restrict__ idx,
    const float* __restrict__ u,
    f16* __restrict__ Tp, f16* __restrict__ EWot, float* __restrict__ cvec) {
  __shared__ __align__(16) f16 sA[2 * 8192], sB[2 * 8192];
  int blk = blockIdx.x;
  if (blk < 256) {
    gemm_core<0>(Egh, G, nullptr, nullptr, Tp, 1024, 1024, (blk >> 3) * 128, (blk & 7) * 128, sA, sB);
  } else if (blk < 512) {
    int t = blk - 256;
    gemm_core<3>(H, Egh, wobk, idx, EWot, 4096, 1024, (t >> 5) * 128, (t & 31) * 128, sA, sB);
  } else {
    int t = blk - 512;
    int w = threadIdx.x >> 6, lane = threadIdx.x & 63;
    int n = t * 4 + w;
    const f16* e = Egh + (size_t)n * 1024;
    float s = 0.f;
#pragma unroll
    for (int i = 0; i < 16; ++i) { int k = lane + i * 64; s += (float)e[k] * u[k]; }
#pragma unroll
    for (int d = 1; d < 64; d <<= 1) s += __shfl_xor(s, d);
    if (lane == 0)
      cvec[n] = s + u[1024] + ((idx[n] < 0) ? -100000.0f : 0.0f);
  }
}

// ================= fused attention v4 + LayerNorm =================
// grid 256: b = id&15 (XCD affinity), lt = id>>4 (16 tiles of 64 Q-rows).
// 4 waves, each owns 64 rows x 64 entity-cols (8 LDS reads per 16 MFMA).
// Single-barrier double-buffered staging, 2-deep register prefetch.
// phase1: S = q@Tp^T (K=1024); phase2: 4-wave softmax; phase3: O=P@EWot^T,
// accumulating LN stats; epilogue: LN from L2-hot O16 re-read -> f32 out.
__global__ __launch_bounds__(256, 1) void attn4(
    const float* __restrict__ query, const f16* __restrict__ Tp,
    const f16* __restrict__ EWot, const float* __restrict__ cvec,
    const float* __restrict__ bo, const float* __restrict__ ln_g,
    const float* __restrict__ ln_b, f16* __restrict__ O16,
    float* __restrict__ out) {
  __shared__ __align__(16) f16 smB[2][256 * 64];   // 64 KB
  __shared__ __align__(16) f16 smQ[2][64 * 64];    // 16 KB
  __shared__ __align__(16) f16 smP[64 * 256];      // 32 KB
  __shared__ float smS[256], smS2[256];            // [wave][row]
  int id = blockIdx.x;
  int b = id & 15, lt = id >> 4;
  int tid = threadIdx.x, lane = tid & 63, w = tid >> 6;
  int l15 = lane & 15, lhi = lane >> 4;
  const float* Qb = query + (size_t)(b * 1024 + lt * 64) * DM;
  const f16* Tb = Tp + (size_t)b * NBE * DM;
  const f16* Eb = EWot + (size_t)b * NBE;          // row stride 4096
  size_t baserow = (size_t)(b * 1024 + lt * 64);

  f32x4 z4 = {0.f, 0.f, 0.f, 0.f};
  f32x4 acc[4][4];
#pragma unroll
  for (int i = 0; i < 4; ++i)
#pragma unroll
    for (int j = 0; j < 4; ++j) acc[i][j] = z4;

  float4 rq[4];
  f16x8 rb[8];
  int qrow = tid >> 2, qc0 = (tid & 3) * 16;
  int srow = tid >> 3, sc8 = tid & 7;              // B-stage: row per p, col-block

  // ---- prologue: load T0, stage buf0, load T1 ----
#pragma unroll
  for (int q = 0; q < 4; ++q) rq[q] = *(const float4*)(Qb + (size_t)qrow * DM + qc0 + q * 4);
#pragma unroll
  for (int p = 0; p < 8; ++p)
    rb[p] = *(const f16x8*)(Tb + (size_t)(p * 32 + srow) * DM + sc8 * 8);
  {
    f16x8 h0, h1;
    h0[0] = (f16)rq[0].x; h0[1] = (f16)rq[0].y; h0[2] = (f16)rq[0].z; h0[3] = (f16)rq[0].w;
    h0[4] = (f16)rq[1].x; h0[5] = (f16)rq[1].y; h0[6] = (f16)rq[1].z; h0[7] = (f16)rq[1].w;
    h1[0] = (f16)rq[2].x; h1[1] = (f16)rq[2].y; h1[2] = (f16)rq[2].z; h1[3] = (f16)rq[2].w;
    h1[4] = (f16)rq[3].x; h1[5] = (f16)rq[3].y; h1[6] = (f16)rq[3].z; h1[7] = (f16)rq[3].w;
    int c8a = (tid & 3) * 2;
    *(f16x8*)(&smQ[0][qrow * 64 + ((c8a ^ (qrow & 7)) << 3)]) = h0;
    *(f16x8*)(&smQ[0][qrow * 64 + (((c8a + 1) ^ (qrow & 7)) << 3)]) = h1;
  }
#pragma unroll
  for (int p = 0; p < 8; ++p) {
    int row = p * 32 + srow;
    *(f16x8*)(&smB[0][row * 64 + ((sc8 ^ (row & 7)) << 3)]) = rb[p];
  }
#pragma unroll
  for (int q = 0; q < 4; ++q) rq[q] = *(const float4*)(Qb + (size_t)qrow * DM + 64 + qc0 + q * 4);
#pragma unroll
  for (int p = 0; p < 8; ++p)
    rb[p] = *(const f16x8*)(Tb + (size_t)(p * 32 + srow) * DM + 64 + sc8 * 8);
  __syncthreads();

  // ---- phase 1: S = q @ Tp^T ----
  for (int kt = 0; kt < 16; ++kt) {
    int cur = kt & 1;
    if (kt < 15) {
      f16x8 h0, h1;
      h0[0] = (f16)rq[0].x; h0[1] = (f16)rq[0].y; h0[2] = (f16)rq[0].z; h0[3] = (f16)rq[0].w;
      h0[4] = (f16)rq[1].x; h0[5] = (f16)rq[1].y; h0[6] = (f16)rq[1].z; h0[7] = (f16)rq[1].w;
      h1[0] = (f16)rq[2].x; h1[1] = (f16)rq[2].y; h1[2] = (f16)rq[2].z; h1[3] = (f16)rq[2].w;
      h1[4] = (f16)rq[3].x; h1[5] = (f16)rq[3].y; h1[6] = (f16)rq[3].z; h1[7] = (f16)rq[3].w;
      int c8a = (tid & 3) * 2;
      *(f16x8*)(&smQ[cur ^ 1][qrow * 64 + ((c8a ^ (qrow & 7)) << 3)]) = h0;
      *(f16x8*)(&smQ[cur ^ 1][qrow * 64 + (((c8a + 1) ^ (qrow & 7)) << 3)]) = h1;
#pragma unroll
      for (int p = 0; p < 8; ++p) {
        int row = p * 32 + srow;
        *(f16x8*)(&smB[cur ^ 1][row * 64 + ((sc8 ^ (row & 7)) << 3)]) = rb[p];
      }
    }
    if (kt < 14) {
#pragma unroll
      for (int q = 0; q < 4; ++q)
        rq[q] = *(const float4*)(Qb + (size_t)qrow * DM + (kt + 2) * 64 + qc0 + q * 4);
#pragma unroll
      for (int p = 0; p < 8; ++p)
        rb[p] = *(const f16x8*)(Tb + (size_t)(p * 32 + srow) * DM + (kt + 2) * 64 + sc8 * 8);
    }
    __builtin_amdgcn_s_setprio(1);
#pragma unroll
    for (int kk = 0; kk < 2; ++kk) {
      int c8 = kk * 4 + lhi;
      f16x8 af[4], bf[4];
#pragma unroll
      for (int mi = 0; mi < 4; ++mi) {
        int r = mi * 16 + l15;
        af[mi] = *(const f16x8*)(&smQ[cur][r * 64 + ((c8 ^ (r & 7)) << 3)]);
      }
#pragma unroll
      for (int ni = 0; ni < 4; ++ni) {
        int er = w * 64 + ni * 16 + l15;
        bf[ni] = *(const f16x8*)(&smB[cur][er * 64 + ((c8 ^ (er & 7)) << 3)]);
      }
#pragma unroll
      for (int mi = 0; mi < 4; ++mi)
#pragma unroll
        for (int ni = 0; ni < 4; ++ni)
          acc[mi][ni] = __builtin_amdgcn_mfma_f32_16x16x32_f16(af[mi], bf[ni], acc[mi][ni], 0, 0, 0);
    }
    __builtin_amdgcn_s_setprio(0);
    __syncthreads();
  }

  // prefetch phase-3 tile 0 (dc=0, ks=0) — overlaps softmax
#pragma unroll
  for (int p = 0; p < 8; ++p)
    rb[p] = *(const f16x8*)(Eb + (size_t)(p * 32 + srow) * 4096 + sc8 * 8);

  // ---- phase 2: softmax (4-wave combine; cvec has mask folded) ----
  float cv[4];
#pragma unroll
  for (int ni = 0; ni < 4; ++ni)
    cv[ni] = cvec[b * NBE + w * 64 + ni * 16 + l15];
#pragma unroll
  for (int mi = 0; mi < 4; ++mi)
#pragma unroll
    for (int j = 0; j < 4; ++j) {
      float m = -3.0e38f;
#pragma unroll
      for (int ni = 0; ni < 4; ++ni) m = fmaxf(m, acc[mi][ni][j] + cv[ni]);
      m = fmaxf(m, __shfl_xor(m, 1));
      m = fmaxf(m, __shfl_xor(m, 2));
      m = fmaxf(m, __shfl_xor(m, 4));
      m = fmaxf(m, __shfl_xor(m, 8));
      if (l15 == 0) smS[w * 64 + mi * 16 + lhi * 4 + j] = m;
    }
  __syncthreads();
#pragma unroll
  for (int mi = 0; mi < 4; ++mi)
#pragma unroll
    for (int j = 0; j < 4; ++j) {
      int r = mi * 16 + lhi * 4 + j;
      float fm = fmaxf(fmaxf(smS[r], smS[64 + r]), fmaxf(smS[128 + r], smS[192 + r]));
      float s = 0.f;
#pragma unroll
      for (int ni = 0; ni < 4; ++ni) {
        float e = __expf(acc[mi][ni][j] + cv[ni] - fm);
        acc[mi][ni][j] = e;
        s += e;
      }
      s += __shfl_xor(s, 1);
      s += __shfl_xor(s, 2);
      s += __shfl_xor(s, 4);
      s += __shfl_xor(s, 8);
      if (l15 == 0) smS2[w * 64 + r] = s;
    }
  __syncthreads();
#pragma unroll
  for (int mi = 0; mi < 4; ++mi)
#pragma unroll
    for (int j = 0; j < 4; ++j) {
      int r = mi * 16 + lhi * 4 + j;
      float inv = 0.03125f / (smS2[r] + smS2[64 + r] + smS2[128 + r] + smS2[192 + r]);
#pragma unroll
      for (int ni = 0; ni < 4; ++ni) {
        int col = w * 64 + ni * 16 + l15;
        int cc8 = col >> 3;
        smP[r * 256 + ((cc8 ^ (r & 7)) << 3) + (col & 7)] = (f16)(acc[mi][ni][j] * inv);
      }
    }

  // stage phase-3 buf0, then load tile 1
#pragma unroll
  for (int p = 0; p < 8; ++p) {
    int row = p * 32 + srow;
    *(f16x8*)(&smB[0][row * 64 + ((sc8 ^ (row & 7)) << 3)]) = rb[p];
  }
  __syncthreads();   // P + buf0 visible
#pragma unroll
  for (int p = 0; p < 8; ++p)
    rb[p] = *(const f16x8*)(Eb + (size_t)(p * 32 + srow) * 4096 + 64 + sc8 * 8);

  // ---- phase 3: O = P @ EWot^T, with LN stats ----
  float sum_[4][4], sq_[4][4];
#pragma unroll
  for (int mi = 0; mi < 4; ++mi)
#pragma unroll
    for (int j = 0; j < 4; ++j) { sum_[mi][j] = 0.f; sq_[mi][j] = 0.f; }
  f32x4 accv[4][4];

  for (int t = 0; t < 16; ++t) {
    int cur = t & 1;
    if ((t & 3) == 0) {
#pragma unroll
      for (int i = 0; i < 4; ++i)
#pragma unroll
        for (int j = 0; j < 4; ++j) accv[i][j] = z4;
    }
    if (t < 15) {
#pragma unroll
      for (int p = 0; p < 8; ++p) {
        int row = p * 32 + srow;
        *(f16x8*)(&smB[cur ^ 1][row * 64 + ((sc8 ^ (row & 7)) << 3)]) = rb[p];
      }
    }
    if (t < 14) {
      int nt = t + 2;
#pragma unroll
      for (int p = 0; p < 8; ++p)
        rb[p] = *(const f16x8*)(Eb + (size_t)((nt >> 2) * 256 + p * 32 + srow) * 4096 + (nt & 3) * 64 + sc8 * 8);
    }
    __builtin_amdgcn_s_setprio(1);
#pragma unroll
    for (int kk = 0; kk < 2; ++kk) {
      int pc8 = (t & 3) * 8 + kk * 4 + lhi;
      int c8 = kk * 4 + lhi;
      f16x8 ap[4], bf[4];
#pragma unroll
      for (int mi = 0; mi < 4; ++mi) {
        int qr = mi * 16 + l15;
        ap[mi] = *(const f16x8*)(&smP[qr * 256 + ((pc8 ^ (qr & 7)) << 3)]);
      }
#pragma unroll
      for (int ni = 0; ni < 4; ++ni) {
        int er = w * 64 + ni * 16 + l15;
        bf[ni] = *(const f16x8*)(&smB[cur][er * 64 + ((c8 ^ (er & 7)) << 3)]);
      }
#pragma unroll
      for (int mi = 0; mi < 4; ++mi)
#pragma unroll
        for (int ni = 0; ni < 4; ++ni)
          accv[mi][ni] = __builtin_amdgcn_mfma_f32_16x16x32_f16(ap[mi], bf[ni], accv[mi][ni], 0, 0, 0);
    }
    __builtin_amdgcn_s_setprio(0);
    if ((t & 3) == 3) {
      int dc = t >> 2;
#pragma unroll
      for (int ni = 0; ni < 4; ++ni) {
        int col = dc * 256 + w * 64 + ni * 16 + l15;
        float bov = bo[col];
#pragma unroll
        for (int mi = 0; mi < 4; ++mi)
#pragma unroll
          for (int j = 0; j < 4; ++j) {
            float v = accv[mi][ni][j] + bov;
            int r = mi * 16 + lhi * 4 + j;
            O16[(baserow + r) * DM + col] = (f16)v;
            sum_[mi][j] += v;
            sq_[mi][j] += v * v;
          }
      }
    }
    __syncthreads();
  }

  // ---- epilogue: LayerNorm ----
  asm volatile("s_waitcnt vmcnt(0)" ::: "memory");
#pragma unroll
  for (int mi = 0; mi < 4; ++mi)
#pragma unroll
    for (int j = 0; j < 4; ++j) {
      float s = sum_[mi][j], q = sq_[mi][j];
      s += __shfl_xor(s, 1); q += __shfl_xor(q, 1);
      s += __shfl_xor(s, 2); q += __shfl_xor(q, 2);
      s += __shfl_xor(s, 4); q += __shfl_xor(q, 4);
      s += __shfl_xor(s, 8); q += __shfl_xor(q, 8);
      if (l15 == 0) {
        smS[w * 64 + mi * 16 + lhi * 4 + j] = s;
        smS2[w * 64 + mi * 16 + lhi * 4 + j] = q;
      }
    }
  __syncthreads();
  float gv[4][4], bv[4][4];
#pragma unroll
  for (int dc = 0; dc < 4; ++dc)
#pragma unroll
    for (int ni = 0; ni < 4; ++ni) {
      int col = dc * 256 + w * 64 + ni * 16 + l15;
      gv[dc][ni] = ln_g[col];
      bv[dc][ni] = ln_b[col];
    }
#pragma unroll
  for (int mi = 0; mi < 4; ++mi)
#pragma unroll
    for (int j = 0; j < 4; ++j) {
      int r = mi * 16 + lhi * 4 + j;
      float S = smS[r] + smS[64 + r] + smS[128 + r] + smS[192 + r];
      float Q2 = smS2[r] + smS2[64 + r] + smS2[128 + r] + smS2[192 + r];
      float mu = S * (1.0f / DM);
      float var = Q2 * (1.0f / DM) - mu * mu;
      float rs = rsqrtf(var + 1e-5f);
#pragma unroll
      for (int dc = 0; dc < 4; ++dc)
#pragma unroll
        for (int ni = 0; ni < 4; ++ni) {
          int col = dc * 256 + w * 64 + ni * 16 + l15;
          float h = (float)O16[(baserow + r) * DM + col];
          out[(baserow + r) * DM + col] = (h - mu) * rs * gv[dc][ni] + bv[dc][ni];
        }
    }
}

extern "C" void kernel_launch(void* const* d_in, const int* in_sizes, int n_in,
                              void* d_out, int out_size, void* d_ws, size_t ws_size,
                              hipStream_t stream) {
  const float* query   = (const float*)d_in[0];
  const float* ent_emb = (const float*)d_in[1];
  const int*   idx     = (const int*)d_in[2];
  const float* WQ_w = (const float*)d_in[4];
  const float* WQ_b = (const float*)d_in[5];
  const float* WK_w = (const float*)d_in[6];
  const float* WK_b = (const float*)d_in[7];
  const float* WO_w = (const float*)d_in[8];
  const float* WO_b = (const float*)d_in[9];
  const float* ln_g = (const float*)d_in[10];
  const float* ln_b = (const float*)d_in[11];
  float* out = (float*)d_out;

  char* p = (char*)d_ws;
  f16* Egh  = (f16*)p;  p += (size_t)4096 * 1024 * 2;        // 8MB
  f16* WQt  = (f16*)p;  p += (size_t)1024 * 1024 * 2;
  f16* WKt  = (f16*)p;  p += (size_t)1024 * 1024 * 2;
  f16* WOr  = (f16*)p;  p += (size_t)1024 * 1024 * 2;
  f16* G    = (f16*)p;  p += (size_t)1024 * 1024 * 2;
  f16* H    = (f16*)p;  p += (size_t)1024 * 1024 * 2;
  f16* Tp   = (f16*)p;  p += (size_t)4096 * 1024 * 2;        // 8MB
  f16* EWot = (f16*)p;  p += (size_t)1024 * 4096 * 2;        // 8MB
  f16* O16  = (f16*)p;  p += (size_t)16384 * 1024 * 2;       // 32MB
  float* u    = (float*)p; p += 1025 * 4;
  float* wobk = (float*)p; p += 1024 * 4;
  float* cvec = (float*)p; p += 4096 * 4;

  hipMemsetAsync(u, 0, 1025 * sizeof(float), stream);
  // fused prep: conv(WO), tr(WQ,WK), gather, u (atomic), bk.bq, wobk
  prep<<<5905, 256, 0, stream>>>(WO_w, WOr, WQ_w, WK_w, WQt, WKt,
                                 ent_emb, idx, Egh, WQ_b, WK_b, u, wobk);
  // G = WQ^T WK ; H = WO WK
  gemm_dual<<<dim3(8, 8, 2), 256, 0, stream>>>(WQt, WOr, WKt, G, H, 1024, 1024);
  // Tp = Eg @ G^T ; EWot = H @ Eg^T + wobk (masked) ; cvec (+mask fold)
  gemm_pair<<<1536, 256, 0, stream>>>(Egh, G, H, wobk, idx, u, Tp, EWot, cvec);
  // fused attention + LayerNorm -> out
  attn4<<<256, 256, 0, stream>>>(query, Tp, EWot, cvec, WO_b, ln_g, ln_b, O16, out);
}